// Round 17
// baseline (4394.294 us; speedup 1.0000x reference)
//
#include <hip/hip_runtime.h>
#include <stdint.h>

typedef __attribute__((ext_vector_type(8))) short short8;
typedef __attribute__((ext_vector_type(4))) float f32x4;

#define MFMA16(a, b, c) __builtin_amdgcn_mfma_f32_16x16x32_bf16((a), (b), (c), 0, 0, 0)
#define AL(p) __hip_atomic_load((p), __ATOMIC_RELAXED, __HIP_MEMORY_SCOPE_AGENT)
#define AS(p, v) __hip_atomic_store((p), (v), __ATOMIC_RELAXED, __HIP_MEMORY_SCOPE_AGENT)

__device__ __forceinline__ unsigned short f2bf(float f) {
  unsigned u = __float_as_uint(f);
  u = (u + 0x7FFFu + ((u >> 16) & 1u)) >> 16;   // RNE
  return (unsigned short)u;
}
__device__ __forceinline__ float bf2f(unsigned short u) {
  return __uint_as_float(((unsigned)u) << 16);
}

// ---------------- prep: single merged kernel (x cvt + 4 weight cvts + biases) -------
__global__ void k_prep(const float* __restrict__ x,
                       const float* __restrict__ w0, const float* __restrict__ w1,
                       const float* __restrict__ w2, const float* __restrict__ w3,
                       const float* __restrict__ a0, const float* __restrict__ b0,
                       const float* __restrict__ a1, const float* __restrict__ b1,
                       unsigned short* __restrict__ xbf,
                       unsigned short* __restrict__ wbf,
                       float* __restrict__ bias0, float* __restrict__ bias1) {
  const int gid = blockIdx.x * blockDim.x + threadIdx.x;
  const int stride = gridDim.x * blockDim.x;
  for (int i = gid; i < 8192; i += stride) {
    if (i < 4096) bias0[i] = a0[i] + b0[i];
    else          bias1[i - 4096] = a1[i - 4096] + b1[i - 4096];
  }
  for (int i = gid; i < 8388608; i += stride) {
    float4 v = reinterpret_cast<const float4*>(x)[i];
    ushort4 o;
    o.x = f2bf(v.x); o.y = f2bf(v.y); o.z = f2bf(v.z); o.w = f2bf(v.w);
    reinterpret_cast<ushort4*>(xbf)[i] = o;
  }
  for (int i = gid; i < 4194304; i += stride) {
    const float* sp = (i < 1048576) ? w0 : (i < 2097152) ? w1
                     : (i < 3145728) ? w2 : w3;
    float4 v = reinterpret_cast<const float4*>(sp)[i & 1048575];
    ushort4 o;
    o.x = f2bf(v.x); o.y = f2bf(v.y); o.z = f2bf(v.z); o.w = f2bf(v.w);
    reinterpret_cast<ushort4*>(wbf)[i] = o;
  }
}

// ---------------- xp GEMM (layer0): per-column interleaved xp layout ----------------
// XCD swizzle (T1): XCD x = bid%8 covers tn in [4x,4x+4) over all tm ->
// per-XCD B-slice = 1 MB (L2-resident).
__global__ __launch_bounds__(256) void k_gemm(
    const unsigned short* __restrict__ A,
    const unsigned short* __restrict__ W,
    const float* __restrict__ bias,
    unsigned short* __restrict__ out,
    int mode) {
  const int tid = threadIdx.x, l = tid & 63, wv = tid >> 6;
  const int wm = wv >> 1, wn = wv & 1;
  const int bid = blockIdx.x;
  const int swz = ((bid & 7) << 10) + (bid >> 3);   // bijective on [0,8192)
  const int tm = swz & 255, tn = swz >> 8;          // 256 x 32 tiles of 128x128
  const int m_base = tm * 128 + wm * 64;
  const int n_base = tn * 128 + wn * 64;
  const int lr = l & 15, k8 = (l >> 4) << 3;

  size_t a_off[4], b_off[4];
#pragma unroll
  for (int i = 0; i < 4; ++i) {
    int r = m_base + i * 16 + lr;
    int ar = mode ? r : (((r & 63) << 9) + (r >> 6));
    a_off[i] = ((size_t)ar << 10) + k8;
    int nr = n_base + i * 16 + lr;
    b_off[i] = ((size_t)nr << 10) + k8;
  }
  f32x4 acc[4][4] = {};
#pragma unroll 2
  for (int k0 = 0; k0 < 1024; k0 += 32) {
    short8 a[4], b[4];
#pragma unroll
    for (int i = 0; i < 4; ++i) a[i] = *reinterpret_cast<const short8*>(A + a_off[i] + k0);
#pragma unroll
    for (int j = 0; j < 4; ++j) b[j] = *reinterpret_cast<const short8*>(W + b_off[j] + k0);
#pragma unroll
    for (int i = 0; i < 4; ++i)
#pragma unroll
      for (int j = 0; j < 4; ++j) acc[i][j] = MFMA16(a[i], b[j], acc[i][j]);
  }
  const int oq = (l >> 4) << 2, oc = l & 15;
#pragma unroll
  for (int j = 0; j < 4; ++j) {
    int col = n_base + j * 16 + oc;
    int gate = col >> 10, jc = col & 1023;
    size_t cidx = (size_t)((jc << 2) + gate);
    float bs = bias[col];
#pragma unroll
    for (int i = 0; i < 4; ++i) {
      int r0 = m_base + i * 16 + oq;
#pragma unroll
      for (int q = 0; q < 4; ++q)
        out[(((size_t)(r0 + q)) << 12) + cidx] = f2bf(acc[i][j][q] + bs);
    }
  }
}

// ---------------- shared: one xp1 chunk gemm (64 t x 16 b x 128 gate cols) ----------
// R14-proven version (40-phase, plain staging loads, trs aliases part[0..16K)).
__device__ __forceinline__ void gemm_chunk(
    const unsigned short* __restrict__ out0,
    const unsigned short* __restrict__ Wih1,
    const float* __restrict__ bias1,
    unsigned short* __restrict__ xb,
    char* smem, int g, int hc0, int c,
    int tid, int l, int ks, int lr16, int k8) {
  const int cg = (ks << 4) + lr16;
  const int gate = cg >> 5, jl = cg & 31;
  const int wrow = (gate << 10) + hc0 + jl;
  const float bsv = bias1[wrow];
  unsigned short* trs = (unsigned short*)smem;   // first 16 KB, reused post-MFMA

  for (int mb = 0; mb < 16; ++mb) {
    f32x4 acc[4] = {{0.f,0.f,0.f,0.f},{0.f,0.f,0.f,0.f},{0.f,0.f,0.f,0.f},{0.f,0.f,0.f,0.f}};
#pragma unroll 1
    for (int kh = 0; kh < 2; ++kh) {
      short8 st[8];
#pragma unroll
      for (int s = 0; s < 8; ++s) {
        int ch = tid + (s << 9);
        int row = ch >> 6, kc = ch & 63;
        int t = (c << 6) + (mb << 2) + (row >> 4);
        int b = (g << 4) + (row & 15);
        st[s] = *reinterpret_cast<const short8*>(
            out0 + (((size_t)((t << 6) + b)) << 10) + (kh << 9) + (kc << 3));
      }
#pragma unroll
      for (int s = 0; s < 8; ++s) {
        int ch = tid + (s << 9);
        int row = ch >> 6, kc = ch & 63;
        *reinterpret_cast<short8*>(smem + (row << 10) + ((kc ^ (row & 7)) << 4)) = st[s];
      }
      __syncthreads();
#pragma unroll
      for (int kk = 0; kk < 16; ++kk) {
        short8 bfr = *reinterpret_cast<const short8*>(
            Wih1 + ((size_t)wrow << 10) + (kh << 9) + (kk << 5) + k8);
        int kc = (kk << 2) + (k8 >> 3);
#pragma unroll
        for (int mt = 0; mt < 4; ++mt) {
          int row = (mt << 4) + lr16;
          short8 a = *reinterpret_cast<const short8*>(
              smem + (row << 10) + ((kc ^ (row & 7)) << 4));
          acc[mt] = MFMA16(a, bfr, acc[mt]);
        }
      }
      __syncthreads();
    }
    // transpose to interleaved layout in LDS, then 16B sc1 stores
#pragma unroll
    for (int mt = 0; mt < 4; ++mt)
#pragma unroll
      for (int q = 0; q < 4; ++q) {
        int bi = ((l >> 4) << 2) + q;
        trs[(((mt << 4) + bi) << 7) + (jl << 2) + gate] = f2bf(acc[mt][q] + bsv);
      }
    __syncthreads();
#pragma unroll
    for (int s = 0; s < 2; ++s) {
      int ch = (tid << 1) + s;
      short8 v = *reinterpret_cast<const short8*>(trs + (ch << 3));
      unsigned short* dst = xb + (mb << 13) + (ch << 3);
      asm volatile("global_store_dwordx4 %0, %1, off sc0 sc1"
                   :: "v"(dst), "v"(v) : "memory");
    }
    __syncthreads();
  }
  asm volatile("s_waitcnt vmcnt(0)" ::: "memory");
  __syncthreads();
}

// ---------------- layer-0 recurrence + tail producer for partner chunks 5..7 ------
__device__ __forceinline__ void rec0_body(
    const unsigned short* __restrict__ xp,
    const unsigned short* __restrict__ Whh,
    unsigned short* __restrict__ hbuf,
    int* __restrict__ gflags,
    unsigned short* __restrict__ out_bf,
    float* __restrict__ hn, float* __restrict__ cn,
    const unsigned short* __restrict__ Wih1,
    const float* __restrict__ bias1,
    unsigned short* __restrict__ xpp_partner,
    const int* __restrict__ pflag1,
    int* __restrict__ fx_self,
    float* part, int w, int g) {
  const int tid = threadIdx.x;
  const int l = tid & 63, ks = tid >> 6;
  const int hc0 = w << 5;
  const int lr16 = l & 15, k8 = (l >> 4) << 3;

  short8 bf[8][4];
#pragma unroll
  for (int nn = 0; nn < 8; ++nn) {
    const int c_wg = (nn << 4) + lr16;
    const unsigned short* wp =
        Whh + ((size_t)(((c_wg >> 5) << 10) + hc0 + (c_wg & 31)) << 10) + (ks << 7) + k8;
#pragma unroll
    for (int kk = 0; kk < 4; ++kk)
      bf[nn][kk] = *reinterpret_cast<const short8*>(wp + (kk << 5));
  }

  const int arow = (g << 4) + lr16;
  const size_t aoff = ((size_t)arow << 10) + (ks << 7) + k8;

  const int b_l = tid >> 5;
  const int j = tid & 31;
  const int b_g = (g << 4) + b_l;
  const int hcol = hc0 + j;

  float cs = 0.f;

  auto xload = [&](int t) -> uint2 {
    return *reinterpret_cast<const uint2*>(
        xp + (((size_t)((t << 6) + b_g)) << 12) + (hcol << 2));
  };

  auto step = [&](int t, uint2 xv) {
    if (t > 0) {
      const unsigned short* ab = hbuf + ((size_t)(t & 1) << 16) + aoff;
      short8 av[4];
#pragma unroll
      for (int kk = 0; kk < 4; ++kk) {
        const unsigned short* p = ab + (kk << 5);
        asm volatile("global_load_dwordx4 %0, %1, off sc0 sc1"
                     : "=v"(av[kk]) : "v"(p) : "memory");
      }
      asm volatile("s_waitcnt vmcnt(0)" ::: "memory");
      __builtin_amdgcn_sched_barrier(0);
      f32x4 acc[8] = {{0.f,0.f,0.f,0.f},{0.f,0.f,0.f,0.f},{0.f,0.f,0.f,0.f},{0.f,0.f,0.f,0.f},
                      {0.f,0.f,0.f,0.f},{0.f,0.f,0.f,0.f},{0.f,0.f,0.f,0.f},{0.f,0.f,0.f,0.f}};
#pragma unroll
      for (int kk = 0; kk < 4; ++kk)
#pragma unroll
        for (int nn = 0; nn < 8; ++nn)
          acc[nn] = MFMA16(av[kk], bf[nn][kk], acc[nn]);
#pragma unroll
      for (int nn = 0; nn < 8; ++nn)
#pragma unroll
        for (int q = 0; q < 4; ++q) {
          int bq = ((l >> 4) << 2) + q;
          part[(((ks << 4) + bq) << 7) + (nn << 4) + lr16] = acc[nn][q];
        }
    }
    __syncthreads();

    float hv, cv;
    unsigned short h16;
    {
      float gi = bf2f((unsigned short)(xv.x)), gf = bf2f((unsigned short)(xv.x >> 16));
      float gg = bf2f((unsigned short)(xv.y)), go = bf2f((unsigned short)(xv.y >> 16));
      if (t > 0) {
        float si = 0.f, sf = 0.f, sg = 0.f, so = 0.f;
#pragma unroll
        for (int ksx = 0; ksx < 8; ++ksx) {
          const float* p = part + (((ksx << 4) + b_l) << 7) + j;
          si += p[0]; sf += p[32]; sg += p[64]; so += p[96];
        }
        gi += si; gf += sf; gg += sg; go += so;
      }
      float iv = 1.f / (1.f + __expf(-gi));
      float fv = 1.f / (1.f + __expf(-gf));
      float gv = tanhf(gg);
      float ov = 1.f / (1.f + __expf(-go));
      cs = fv * cs + iv * gv;
      hv = ov * tanhf(cs);
      cv = cs;
      h16 = f2bf(hv);
      AS(hbuf + ((size_t)((t + 1) & 1) << 16) + ((size_t)b_g << 10) + hcol, h16);
    }
    asm volatile("s_waitcnt vmcnt(0)" ::: "memory");
    __syncthreads();
    if (tid == 0) AS(&gflags[w], t + 1);

    AS(out_bf + ((((size_t)t << 6) + b_g) << 10) + hcol, h16);
    if (t == 511) {
      hn[((size_t)b_g << 10) + hcol] = hv;
      cn[((size_t)b_g << 10) + hcol] = cv;
    } else {
      const int base = ks << 2;
      for (;;) {
        int f = (l < 4) ? AL(&gflags[base + l]) : 0x7fffffff;
        if (__all(f > t)) break;
        __builtin_amdgcn_s_sleep(1);
      }
    }
  };

  uint2 zz = {0u, 0u};
  uint2 xA[4] = {zz, zz, zz, zz}, xB[4] = {zz, zz, zz, zz};
#pragma unroll
  for (int s = 0; s < 4; ++s) xA[s] = xload(s);
  for (int tc = 0; tc < 512; tc += 8) {
#pragma unroll
    for (int s = 0; s < 4; ++s) xB[s] = xload(tc + 4 + s);
#pragma unroll
    for (int s = 0; s < 4; ++s) step(tc + s, xA[s]);
    if (tc + 8 < 512) {
#pragma unroll
      for (int s = 0; s < 4; ++s) xA[s] = xload(tc + 8 + s);
    }
#pragma unroll
    for (int s = 0; s < 4; ++s) step(tc + 4 + s, xB[s]);
  }

  asm volatile("s_waitcnt vmcnt(0)" ::: "memory");
  __syncthreads();
  if (tid == 0) AS(&gflags[w], 1000);

  // ---- tail producer: partner rec1 WG's xp1 chunks 5..7 ----
  if (tid == 0) {
    for (;;) {
      bool ok = true;
      for (int i = 0; i < 32; ++i)
        if (AL(&gflags[i]) < 1000) { ok = false; break; }
      if (ok) break;
      __builtin_amdgcn_s_sleep(16);
    }
  }
  __syncthreads();
  for (int c = 5; c < 8; ++c) {
    // Slot c&1 holds chunk c-2; rec1 finishes reading it after step
    // t = (c-1)*64 - 1, which posts flag (c-1)*64.
    const int need = (c - 1) << 6;
    if (tid == 0) {
      while (AL(pflag1) < need) __builtin_amdgcn_s_sleep(16);
    }
    __syncthreads();
    gemm_chunk(out_bf, Wih1, bias1,
               xpp_partner + ((size_t)(c & 1) << 17),
               (char*)part, g, hc0, c, tid, l, ks, lr16, k8);
    if (tid == 0) AS(fx_self, c + 1);
  }
}

// ---------------- layer-1: chunks 0..4 self-gemm, 5..7 from partner (fx-gated) ------
__device__ __forceinline__ void layer1_body(
    const unsigned short* __restrict__ out0,
    const unsigned short* __restrict__ Wih1,
    const float* __restrict__ bias1,
    const unsigned short* __restrict__ Whh1,
    unsigned short* __restrict__ xpp,      // private 2 x 131072 ushorts (ping-pong, sc1)
    unsigned short* __restrict__ hbuf,
    int* __restrict__ gflags0,
    int* __restrict__ gflags1,
    const int* __restrict__ fx_self,
    float* __restrict__ outf,
    float* __restrict__ hn, float* __restrict__ cn,
    float* part, int u, int g) {
  const int tid = threadIdx.x;
  const int l = tid & 63, ks = tid >> 6;
  const int hc0 = u << 5;
  const int lr16 = l & 15, k8 = (l >> 4) << 3;

  short8 bf[8][4];
#pragma unroll
  for (int nn = 0; nn < 8; ++nn) {
    const int c_wg = (nn << 4) + lr16;
    const unsigned short* wp =
        Whh1 + ((size_t)(((c_wg >> 5) << 10) + hc0 + (c_wg & 31)) << 10) + (ks << 7) + k8;
#pragma unroll
    for (int kk = 0; kk < 4; ++kk)
      bf[nn][kk] = *reinterpret_cast<const short8*>(wp + (kk << 5));
  }

  const int arow = (g << 4) + lr16;
  const size_t aoff = ((size_t)arow << 10) + (ks << 7) + k8;
  const int b_l = tid >> 5, j = tid & 31;
  const int b_g = (g << 4) + b_l;
  const int hcol = hc0 + j;

  float cs = 0.f;

  for (int c = 0; c < 8; ++c) {
    if (c < 5) {
      // gate on rec0: out0 rows of chunk c certified
      const int thr = ((c + 1) << 6) + 1;
      if (tid == 0) {
        for (;;) {
          bool ok = true;
          for (int i = 0; i < 32; ++i)
            if (AL(&gflags0[i]) < thr) { ok = false; break; }
          if (ok) break;
          __builtin_amdgcn_s_sleep(16);
        }
      }
      __syncthreads();
      gemm_chunk(out0, Wih1, bias1,
                 xpp + ((size_t)(c & 1) << 17),
                 (char*)part, g, hc0, c, tid, l, ks, lr16, k8);
    } else {
      // partner-produced chunk
      if (tid == 0) {
        while (AL(fx_self) < c + 1) __builtin_amdgcn_s_sleep(16);
      }
      __syncthreads();
    }

    const unsigned short* xb = xpp + ((size_t)(c & 1) << 17);
    for (int ti = 0; ti < 64; ++ti) {
      const int t = (c << 6) + ti;
      uint2 xv;
      {
        const unsigned short* p = xb + (((ti << 4) + b_l) << 7) + (j << 2);
        asm volatile("global_load_dwordx2 %0, %1, off sc0 sc1"
                     : "=v"(xv) : "v"(p) : "memory");
      }

      if (t > 0) {
        const unsigned short* ab = hbuf + ((size_t)(t & 1) << 16) + aoff;
        short8 av[4];
#pragma unroll
        for (int kk = 0; kk < 4; ++kk) {
          const unsigned short* p = ab + (kk << 5);
          asm volatile("global_load_dwordx4 %0, %1, off sc0 sc1"
                       : "=v"(av[kk]) : "v"(p) : "memory");
        }
        asm volatile("s_waitcnt vmcnt(0)" ::: "memory");
        __builtin_amdgcn_sched_barrier(0);
        f32x4 acc[8] = {{0.f,0.f,0.f,0.f},{0.f,0.f,0.f,0.f},{0.f,0.f,0.f,0.f},{0.f,0.f,0.f,0.f},
                        {0.f,0.f,0.f,0.f},{0.f,0.f,0.f,0.f},{0.f,0.f,0.f,0.f},{0.f,0.f,0.f,0.f}};
#pragma unroll
        for (int kk = 0; kk < 4; ++kk)
#pragma unroll
          for (int nn = 0; nn < 8; ++nn)
            acc[nn] = MFMA16(av[kk], bf[nn][kk], acc[nn]);
#pragma unroll
        for (int nn = 0; nn < 8; ++nn)
#pragma unroll
          for (int q = 0; q < 4; ++q) {
            int bq = ((l >> 4) << 2) + q;
            part[(((ks << 4) + bq) << 7) + (nn << 4) + lr16] = acc[nn][q];
          }
      } else {
        asm volatile("s_waitcnt vmcnt(0)" ::: "memory");  // xv ready (t==0 path)
      }
      __syncthreads();

      float hv, cv;
      unsigned short h16;
      {
        float gi = bf2f((unsigned short)(xv.x)), gf = bf2f((unsigned short)(xv.x >> 16));
        float gg = bf2f((unsigned short)(xv.y)), go = bf2f((unsigned short)(xv.y >> 16));
        if (t > 0) {
          float si = 0.f, sf = 0.f, sg = 0.f, so = 0.f;
#pragma unroll
          for (int ksx = 0; ksx < 8; ++ksx) {
            const float* p = part + (((ksx << 4) + b_l) << 7) + j;
            si += p[0]; sf += p[32]; sg += p[64]; so += p[96];
          }
          gi += si; gf += sf; gg += sg; go += so;
        }
        float iv = 1.f / (1.f + __expf(-gi));
        float fv = 1.f / (1.f + __expf(-gf));
        float gv = tanhf(gg);
        float ov = 1.f / (1.f + __expf(-go));
        cs = fv * cs + iv * gv;
        hv = ov * tanhf(cs);
        cv = cs;
        h16 = f2bf(hv);
        AS(hbuf + ((size_t)((t + 1) & 1) << 16) + ((size_t)b_g << 10) + hcol, h16);
      }
      asm volatile("s_waitcnt vmcnt(0)" ::: "memory");
      __syncthreads();
      if (tid == 0) AS(&gflags1[u], t + 1);

      outf[((((size_t)b_g << 9) + t) << 10) + hcol] = hv;
      if (t == 511) {
        hn[((size_t)b_g << 10) + hcol] = hv;
        cn[((size_t)b_g << 10) + hcol] = cv;
      } else {
        const int base = ks << 2;
        for (;;) {
          int f = (l < 4) ? AL(&gflags1[base + l]) : 0x7fffffff;
          if (__all(f > t)) break;
          __builtin_amdgcn_s_sleep(1);
        }
      }
    }
  }
}

// ---------------- fused: rec0+tail-producer (0..127) || rec1 (128..255) ------------
__global__ __launch_bounds__(512, 2) void k_fused(
    const unsigned short* __restrict__ xp0,
    const unsigned short* __restrict__ Whh0,
    unsigned short* __restrict__ hb0,
    int* __restrict__ flags0,
    unsigned short* __restrict__ out0,
    float* __restrict__ hn, float* __restrict__ cn,
    const unsigned short* __restrict__ Wih1,
    const float* __restrict__ bias1,
    const unsigned short* __restrict__ Whh1,
    unsigned short* __restrict__ xpp_all,
    unsigned short* __restrict__ hb1,
    int* __restrict__ flags1,
    int* __restrict__ fx,
    float* __restrict__ outf) {
  __shared__ float part[8 * 16 * 128];   // 64 KB
  const int wg = blockIdx.x;
  if (wg < 128) {
    rec0_body(xp0, Whh0, hb0, flags0 + ((wg >> 5) << 8), out0, hn, cn,
              Wih1, bias1,
              xpp_all + ((size_t)wg << 18),
              &flags1[((wg >> 5) << 8) + (wg & 31)],
              &fx[wg],
              part, wg & 31, wg >> 5);
  } else {
    const int w1 = wg - 128;
    layer1_body(out0, Wih1, bias1, Whh1,
                xpp_all + ((size_t)w1 << 18),
                hb1, flags0 + ((w1 >> 5) << 8), flags1 + ((w1 >> 5) << 8),
                &fx[w1],
                outf, hn + 65536, cn + 65536,
                part, w1 & 31, w1 >> 5);
  }
}

// ---------------- launch ----------------
extern "C" void kernel_launch(void* const* d_in, const int* in_sizes, int n_in,
                              void* d_out, int out_size, void* d_ws, size_t ws_size,
                              hipStream_t stream) {
  (void)in_sizes; (void)n_in; (void)out_size; (void)ws_size;
  const float* x    = (const float*)d_in[0];
  const float* Wih0 = (const float*)d_in[1];
  const float* bih0 = (const float*)d_in[2];
  const float* Whh0 = (const float*)d_in[3];
  const float* bhh0 = (const float*)d_in[4];
  const float* Wih1 = (const float*)d_in[5];
  const float* bih1 = (const float*)d_in[6];
  const float* Whh1 = (const float*)d_in[7];
  const float* bhh1 = (const float*)d_in[8];
  float* dout = (float*)d_out;

  char* ws = (char*)d_ws;
  int*            flags0 = (int*)ws;                         // 4 KB
  int*            flags1 = (int*)(ws + 4096);                // 4 KB
  int*            fx     = (int*)(ws + 8192);                // 4 KB (128 used)
  unsigned short* hb0    = (unsigned short*)(ws + 12288);    // 256 KB
  unsigned short* hb1    = (unsigned short*)(ws + 274432);   // 256 KB
  float*          bias0  = (float*)(ws + 536576);            // 16 KB
  float*          bias1  = (float*)(ws + 552960);            // 16 KB
  unsigned short* wbf    = (unsigned short*)(ws + 569344);   // 32 MB: ih0,hh0,ih1,hh1
  unsigned short* xbf    = wbf + 16777216;                   // 64 MB (x bf16; reused as xpp)
  unsigned short* out0   = xbf + 33554432;                   // 64 MB
  unsigned short* xpb    = out0 + 33554432;                  // 256 MB (xp0)

  hipMemsetAsync(flags0, 0, 12288, stream);

  // merged prep: x cvt + 4 weight cvts + biases (one launch)
  k_prep<<<2048, 256, 0, stream>>>(x, Wih0, Whh0, Wih1, Whh1,
                                   bih0, bhh0, bih1, bhh1,
                                   xbf, wbf, bias0, bias1);

  float* hn = dout + 33554432;
  float* cn = dout + 33554432 + 131072;

  // layer 0 xp (serial; xbf becomes dead afterward and is reused as xpp)
  k_gemm<<<8192, 256, 0, stream>>>(xbf, wbf + 0, bias0, xpb, 0);

  // fused pipeline: rec0 (+ tail gemm producer) || rec1
  k_fused<<<256, 512, 0, stream>>>(xpb, wbf + 4194304, hb0, flags0,
                                   out0, hn, cn,
                                   wbf + 8388608, bias1, wbf + 12582912,
                                   xbf, hb1, flags1, fx, dout);
}

// Round 18
// 4063.170 us; speedup vs baseline: 1.0815x; 1.0815x over previous
//
#include <hip/hip_runtime.h>
#include <stdint.h>

typedef __attribute__((ext_vector_type(8))) short short8;
typedef __attribute__((ext_vector_type(4))) float f32x4;

#define MFMA16(a, b, c) __builtin_amdgcn_mfma_f32_16x16x32_bf16((a), (b), (c), 0, 0, 0)
#define AL(p) __hip_atomic_load((p), __ATOMIC_RELAXED, __HIP_MEMORY_SCOPE_AGENT)
#define AS(p, v) __hip_atomic_store((p), (v), __ATOMIC_RELAXED, __HIP_MEMORY_SCOPE_AGENT)

__device__ __forceinline__ unsigned short f2bf(float f) {
  unsigned u = __float_as_uint(f);
  u = (u + 0x7FFFu + ((u >> 16) & 1u)) >> 16;   // RNE
  return (unsigned short)u;
}
__device__ __forceinline__ float bf2f(unsigned short u) {
  return __uint_as_float(((unsigned)u) << 16);
}

// ---------------- prep: single merged kernel (x cvt + 4 weight cvts + biases) -------
__global__ void k_prep(const float* __restrict__ x,
                       const float* __restrict__ w0, const float* __restrict__ w1,
                       const float* __restrict__ w2, const float* __restrict__ w3,
                       const float* __restrict__ a0, const float* __restrict__ b0,
                       const float* __restrict__ a1, const float* __restrict__ b1,
                       unsigned short* __restrict__ xbf,
                       unsigned short* __restrict__ wbf,
                       float* __restrict__ bias0, float* __restrict__ bias1) {
  const int gid = blockIdx.x * blockDim.x + threadIdx.x;
  const int stride = gridDim.x * blockDim.x;
  for (int i = gid; i < 8192; i += stride) {
    if (i < 4096) bias0[i] = a0[i] + b0[i];
    else          bias1[i - 4096] = a1[i - 4096] + b1[i - 4096];
  }
  for (int i = gid; i < 8388608; i += stride) {
    float4 v = reinterpret_cast<const float4*>(x)[i];
    ushort4 o;
    o.x = f2bf(v.x); o.y = f2bf(v.y); o.z = f2bf(v.z); o.w = f2bf(v.w);
    reinterpret_cast<ushort4*>(xbf)[i] = o;
  }
  for (int i = gid; i < 4194304; i += stride) {
    const float* sp = (i < 1048576) ? w0 : (i < 2097152) ? w1
                     : (i < 3145728) ? w2 : w3;
    float4 v = reinterpret_cast<const float4*>(sp)[i & 1048575];
    ushort4 o;
    o.x = f2bf(v.x); o.y = f2bf(v.y); o.z = f2bf(v.z); o.w = f2bf(v.w);
    reinterpret_cast<ushort4*>(wbf)[i] = o;
  }
}

// ---------------- xp GEMM (layer0): per-column interleaved xp layout ----------------
__global__ __launch_bounds__(256) void k_gemm(
    const unsigned short* __restrict__ A,
    const unsigned short* __restrict__ W,
    const float* __restrict__ bias,
    unsigned short* __restrict__ out,
    int mode) {
  const int tid = threadIdx.x, l = tid & 63, wv = tid >> 6;
  const int wm = wv >> 1, wn = wv & 1;
  const int tm = blockIdx.x >> 5, tn = blockIdx.x & 31;
  const int m_base = tm * 128 + wm * 64;
  const int n_base = tn * 128 + wn * 64;
  const int lr = l & 15, k8 = (l >> 4) << 3;

  size_t a_off[4], b_off[4];
#pragma unroll
  for (int i = 0; i < 4; ++i) {
    int r = m_base + i * 16 + lr;
    int ar = mode ? r : (((r & 63) << 9) + (r >> 6));
    a_off[i] = ((size_t)ar << 10) + k8;
    int nr = n_base + i * 16 + lr;
    b_off[i] = ((size_t)nr << 10) + k8;
  }
  f32x4 acc[4][4] = {};
#pragma unroll 2
  for (int k0 = 0; k0 < 1024; k0 += 32) {
    short8 a[4], b[4];
#pragma unroll
    for (int i = 0; i < 4; ++i) a[i] = *reinterpret_cast<const short8*>(A + a_off[i] + k0);
#pragma unroll
    for (int j = 0; j < 4; ++j) b[j] = *reinterpret_cast<const short8*>(W + b_off[j] + k0);
#pragma unroll
    for (int i = 0; i < 4; ++i)
#pragma unroll
      for (int j = 0; j < 4; ++j) acc[i][j] = MFMA16(a[i], b[j], acc[i][j]);
  }
  const int oq = (l >> 4) << 2, oc = l & 15;
#pragma unroll
  for (int j = 0; j < 4; ++j) {
    int col = n_base + j * 16 + oc;
    int gate = col >> 10, jc = col & 1023;
    size_t cidx = (size_t)((jc << 2) + gate);
    float bs = bias[col];
#pragma unroll
    for (int i = 0; i < 4; ++i) {
      int r0 = m_base + i * 16 + oq;
#pragma unroll
      for (int q = 0; q < 4; ++q)
        out[(((size_t)(r0 + q)) << 12) + cidx] = f2bf(acc[i][j][q] + bs);
    }
  }
}

// ---------------- shared: one xp1 chunk gemm with PER-MB producer gating ------------
// mb reads out0 timesteps [64c+4mb, 64c+4mb+4), certified at flag 64c+4mb+5
// (out0[t] certified at flag t+2: t's store drains before flag t+2 posts).
// gmin_lds caches the observed min flag -> steady-state chunks poll once.
__device__ __forceinline__ void gemm_chunk(
    const unsigned short* __restrict__ out0,
    const unsigned short* __restrict__ Wih1,
    const float* __restrict__ bias1,
    unsigned short* __restrict__ xb,
    const int* __restrict__ gf0,
    int* __restrict__ gmin_lds,
    char* smem, int g, int hc0, int c,
    int tid, int l, int ks, int lr16, int k8) {
  const int cg = (ks << 4) + lr16;
  const int gate = cg >> 5, jl = cg & 31;
  const int wrow = (gate << 10) + hc0 + jl;
  const float bsv = bias1[wrow];
  unsigned short* trs = (unsigned short*)smem;   // first 16 KB, reused post-MFMA

  int gmin = 0;
  for (int mb = 0; mb < 16; ++mb) {
    // ---- per-mb producer gate ----
    const int thr = (c << 6) + (mb << 2) + 5;
    if (gmin < thr) {
      if (tid == 0) {
        int m;
        for (;;) {
          m = 0x7fffffff;
          for (int i = 0; i < 32; ++i) { int f = AL(&gf0[i]); m = (f < m) ? f : m; }
          if (m >= thr) break;
          __builtin_amdgcn_s_sleep(4);
        }
        *gmin_lds = m;
      }
      __syncthreads();
      gmin = *gmin_lds;
    }

    f32x4 acc[4] = {{0.f,0.f,0.f,0.f},{0.f,0.f,0.f,0.f},{0.f,0.f,0.f,0.f},{0.f,0.f,0.f,0.f}};
#pragma unroll 1
    for (int kh = 0; kh < 2; ++kh) {
      short8 st[8];
#pragma unroll
      for (int s = 0; s < 8; ++s) {
        int ch = tid + (s << 9);
        int row = ch >> 6, kc = ch & 63;
        int t = (c << 6) + (mb << 2) + (row >> 4);
        int b = (g << 4) + (row & 15);
        st[s] = *reinterpret_cast<const short8*>(
            out0 + (((size_t)((t << 6) + b)) << 10) + (kh << 9) + (kc << 3));
      }
#pragma unroll
      for (int s = 0; s < 8; ++s) {
        int ch = tid + (s << 9);
        int row = ch >> 6, kc = ch & 63;
        *reinterpret_cast<short8*>(smem + (row << 10) + ((kc ^ (row & 7)) << 4)) = st[s];
      }
      __syncthreads();
#pragma unroll
      for (int kk = 0; kk < 16; ++kk) {
        short8 bfr = *reinterpret_cast<const short8*>(
            Wih1 + ((size_t)wrow << 10) + (kh << 9) + (kk << 5) + k8);
        int kc = (kk << 2) + (k8 >> 3);
#pragma unroll
        for (int mt = 0; mt < 4; ++mt) {
          int row = (mt << 4) + lr16;
          short8 a = *reinterpret_cast<const short8*>(
              smem + (row << 10) + ((kc ^ (row & 7)) << 4));
          acc[mt] = MFMA16(a, bfr, acc[mt]);
        }
      }
      __syncthreads();
    }
    // transpose to interleaved layout in LDS, then 16B sc1 stores
#pragma unroll
    for (int mt = 0; mt < 4; ++mt)
#pragma unroll
      for (int q = 0; q < 4; ++q) {
        int bi = ((l >> 4) << 2) + q;
        trs[(((mt << 4) + bi) << 7) + (jl << 2) + gate] = f2bf(acc[mt][q] + bsv);
      }
    __syncthreads();
#pragma unroll
    for (int s = 0; s < 2; ++s) {
      int ch = (tid << 1) + s;
      short8 v = *reinterpret_cast<const short8*>(trs + (ch << 3));
      unsigned short* dst = xb + (mb << 13) + (ch << 3);
      asm volatile("global_store_dwordx4 %0, %1, off sc0 sc1"
                   :: "v"(dst), "v"(v) : "memory");
    }
    __syncthreads();
  }
  asm volatile("s_waitcnt vmcnt(0)" ::: "memory");
  __syncthreads();
}

// ---------------- layer-0 recurrence + tail producer for partner chunks 5..7 ------
__device__ __forceinline__ void rec0_body(
    const unsigned short* __restrict__ xp,
    const unsigned short* __restrict__ Whh,
    unsigned short* __restrict__ hbuf,
    int* __restrict__ gflags,
    unsigned short* __restrict__ out_bf,
    float* __restrict__ hn, float* __restrict__ cn,
    const unsigned short* __restrict__ Wih1,
    const float* __restrict__ bias1,
    unsigned short* __restrict__ xpp_partner,
    const int* __restrict__ pflag1,
    int* __restrict__ fx_self,
    float* part, int* gmin_lds, int w, int g) {
  const int tid = threadIdx.x;
  const int l = tid & 63, ks = tid >> 6;
  const int hc0 = w << 5;
  const int lr16 = l & 15, k8 = (l >> 4) << 3;

  short8 bf[8][4];
#pragma unroll
  for (int nn = 0; nn < 8; ++nn) {
    const int c_wg = (nn << 4) + lr16;
    const unsigned short* wp =
        Whh + ((size_t)(((c_wg >> 5) << 10) + hc0 + (c_wg & 31)) << 10) + (ks << 7) + k8;
#pragma unroll
    for (int kk = 0; kk < 4; ++kk)
      bf[nn][kk] = *reinterpret_cast<const short8*>(wp + (kk << 5));
  }

  const int arow = (g << 4) + lr16;
  const size_t aoff = ((size_t)arow << 10) + (ks << 7) + k8;

  const int b_l = tid >> 5;
  const int j = tid & 31;
  const int b_g = (g << 4) + b_l;
  const int hcol = hc0 + j;

  float cs = 0.f;

  auto xload = [&](int t) -> uint2 {
    return *reinterpret_cast<const uint2*>(
        xp + (((size_t)((t << 6) + b_g)) << 12) + (hcol << 2));
  };

  auto step = [&](int t, uint2 xv) {
    if (t > 0) {
      const unsigned short* ab = hbuf + ((size_t)(t & 1) << 16) + aoff;
      short8 av[4];
#pragma unroll
      for (int kk = 0; kk < 4; ++kk) {
        const unsigned short* p = ab + (kk << 5);
        asm volatile("global_load_dwordx4 %0, %1, off sc0 sc1"
                     : "=v"(av[kk]) : "v"(p) : "memory");
      }
      asm volatile("s_waitcnt vmcnt(0)" ::: "memory");
      __builtin_amdgcn_sched_barrier(0);
      f32x4 acc[8] = {{0.f,0.f,0.f,0.f},{0.f,0.f,0.f,0.f},{0.f,0.f,0.f,0.f},{0.f,0.f,0.f,0.f},
                      {0.f,0.f,0.f,0.f},{0.f,0.f,0.f,0.f},{0.f,0.f,0.f,0.f},{0.f,0.f,0.f,0.f}};
#pragma unroll
      for (int kk = 0; kk < 4; ++kk)
#pragma unroll
        for (int nn = 0; nn < 8; ++nn)
          acc[nn] = MFMA16(av[kk], bf[nn][kk], acc[nn]);
#pragma unroll
      for (int nn = 0; nn < 8; ++nn)
#pragma unroll
        for (int q = 0; q < 4; ++q) {
          int bq = ((l >> 4) << 2) + q;
          part[(((ks << 4) + bq) << 7) + (nn << 4) + lr16] = acc[nn][q];
        }
    }
    __syncthreads();

    float hv, cv;
    unsigned short h16;
    {
      float gi = bf2f((unsigned short)(xv.x)), gf = bf2f((unsigned short)(xv.x >> 16));
      float gg = bf2f((unsigned short)(xv.y)), go = bf2f((unsigned short)(xv.y >> 16));
      if (t > 0) {
        float si = 0.f, sf = 0.f, sg = 0.f, so = 0.f;
#pragma unroll
        for (int ksx = 0; ksx < 8; ++ksx) {
          const float* p = part + (((ksx << 4) + b_l) << 7) + j;
          si += p[0]; sf += p[32]; sg += p[64]; so += p[96];
        }
        gi += si; gf += sf; gg += sg; go += so;
      }
      float iv = 1.f / (1.f + __expf(-gi));
      float fv = 1.f / (1.f + __expf(-gf));
      float gv = tanhf(gg);
      float ov = 1.f / (1.f + __expf(-go));
      cs = fv * cs + iv * gv;
      hv = ov * tanhf(cs);
      cv = cs;
      h16 = f2bf(hv);
      AS(hbuf + ((size_t)((t + 1) & 1) << 16) + ((size_t)b_g << 10) + hcol, h16);
    }
    asm volatile("s_waitcnt vmcnt(0)" ::: "memory");
    __syncthreads();
    if (tid == 0) AS(&gflags[w], t + 1);

    AS(out_bf + ((((size_t)t << 6) + b_g) << 10) + hcol, h16);
    if (t == 511) {
      hn[((size_t)b_g << 10) + hcol] = hv;
      cn[((size_t)b_g << 10) + hcol] = cv;
    } else {
      const int base = ks << 2;
      for (;;) {
        int f = (l < 4) ? AL(&gflags[base + l]) : 0x7fffffff;
        if (__all(f > t)) break;
        __builtin_amdgcn_s_sleep(1);
      }
    }
  };

  uint2 zz = {0u, 0u};
  uint2 xA[4] = {zz, zz, zz, zz}, xB[4] = {zz, zz, zz, zz};
#pragma unroll
  for (int s = 0; s < 4; ++s) xA[s] = xload(s);
  for (int tc = 0; tc < 512; tc += 8) {
#pragma unroll
    for (int s = 0; s < 4; ++s) xB[s] = xload(tc + 4 + s);
#pragma unroll
    for (int s = 0; s < 4; ++s) step(tc + s, xA[s]);
    if (tc + 8 < 512) {
#pragma unroll
      for (int s = 0; s < 4; ++s) xA[s] = xload(tc + 8 + s);
    }
#pragma unroll
    for (int s = 0; s < 4; ++s) step(tc + 4 + s, xB[s]);
  }

  asm volatile("s_waitcnt vmcnt(0)" ::: "memory");
  __syncthreads();
  if (tid == 0) AS(&gflags[w], 1000);

  // ---- tail producer: partner rec1 WG's xp1 chunks 5..7 ----
  if (tid == 0) {
    for (;;) {
      bool ok = true;
      for (int i = 0; i < 32; ++i)
        if (AL(&gflags[i]) < 1000) { ok = false; break; }
      if (ok) break;
      __builtin_amdgcn_s_sleep(16);
    }
  }
  __syncthreads();
  for (int c = 5; c < 8; ++c) {
    // Slot c&1 holds chunk c-2; rec1 finishes reading it after step
    // t = (c-1)*64 - 1, which posts flag (c-1)*64.
    const int need = (c - 1) << 6;
    if (tid == 0) {
      while (AL(pflag1) < need) __builtin_amdgcn_s_sleep(16);
    }
    __syncthreads();
    gemm_chunk(out_bf, Wih1, bias1,
               xpp_partner + ((size_t)(c & 1) << 17),
               gflags, gmin_lds,
               (char*)part, g, hc0, c, tid, l, ks, lr16, k8);
    if (tid == 0) AS(fx_self, c + 1);
  }
}

// ---------------- layer-1: chunks 0..4 self-gemm (mb-paced), 5..7 from partner ------
__device__ __forceinline__ void layer1_body(
    const unsigned short* __restrict__ out0,
    const unsigned short* __restrict__ Wih1,
    const float* __restrict__ bias1,
    const unsigned short* __restrict__ Whh1,
    unsigned short* __restrict__ xpp,      // private 2 x 131072 ushorts (ping-pong, sc1)
    unsigned short* __restrict__ hbuf,
    int* __restrict__ gflags0,
    int* __restrict__ gflags1,
    const int* __restrict__ fx_self,
    float* __restrict__ outf,
    float* __restrict__ hn, float* __restrict__ cn,
    float* part, int* gmin_lds, int u, int g) {
  const int tid = threadIdx.x;
  const int l = tid & 63, ks = tid >> 6;
  const int hc0 = u << 5;
  const int lr16 = l & 15, k8 = (l >> 4) << 3;

  short8 bf[8][4];
#pragma unroll
  for (int nn = 0; nn < 8; ++nn) {
    const int c_wg = (nn << 4) + lr16;
    const unsigned short* wp =
        Whh1 + ((size_t)(((c_wg >> 5) << 10) + hc0 + (c_wg & 31)) << 10) + (ks << 7) + k8;
#pragma unroll
    for (int kk = 0; kk < 4; ++kk)
      bf[nn][kk] = *reinterpret_cast<const short8*>(wp + (kk << 5));
  }

  const int arow = (g << 4) + lr16;
  const size_t aoff = ((size_t)arow << 10) + (ks << 7) + k8;
  const int b_l = tid >> 5, j = tid & 31;
  const int b_g = (g << 4) + b_l;
  const int hcol = hc0 + j;

  float cs = 0.f;

  for (int c = 0; c < 8; ++c) {
    if (c < 5) {
      // self-gemm, per-mb paced against rec0 (no whole-chunk gate needed;
      // xpp slot c&1 was last read by THIS WG in chunk c-2 -> program order)
      gemm_chunk(out0, Wih1, bias1,
                 xpp + ((size_t)(c & 1) << 17),
                 gflags0, gmin_lds,
                 (char*)part, g, hc0, c, tid, l, ks, lr16, k8);
    } else {
      // partner-produced chunk
      if (tid == 0) {
        while (AL(fx_self) < c + 1) __builtin_amdgcn_s_sleep(16);
      }
      __syncthreads();
    }

    const unsigned short* xb = xpp + ((size_t)(c & 1) << 17);
    for (int ti = 0; ti < 64; ++ti) {
      const int t = (c << 6) + ti;
      uint2 xv;
      {
        const unsigned short* p = xb + (((ti << 4) + b_l) << 7) + (j << 2);
        asm volatile("global_load_dwordx2 %0, %1, off sc0 sc1"
                     : "=v"(xv) : "v"(p) : "memory");
      }

      if (t > 0) {
        const unsigned short* ab = hbuf + ((size_t)(t & 1) << 16) + aoff;
        short8 av[4];
#pragma unroll
        for (int kk = 0; kk < 4; ++kk) {
          const unsigned short* p = ab + (kk << 5);
          asm volatile("global_load_dwordx4 %0, %1, off sc0 sc1"
                       : "=v"(av[kk]) : "v"(p) : "memory");
        }
        asm volatile("s_waitcnt vmcnt(0)" ::: "memory");
        __builtin_amdgcn_sched_barrier(0);
        f32x4 acc[8] = {{0.f,0.f,0.f,0.f},{0.f,0.f,0.f,0.f},{0.f,0.f,0.f,0.f},{0.f,0.f,0.f,0.f},
                        {0.f,0.f,0.f,0.f},{0.f,0.f,0.f,0.f},{0.f,0.f,0.f,0.f},{0.f,0.f,0.f,0.f}};
#pragma unroll
        for (int kk = 0; kk < 4; ++kk)
#pragma unroll
          for (int nn = 0; nn < 8; ++nn)
            acc[nn] = MFMA16(av[kk], bf[nn][kk], acc[nn]);
#pragma unroll
        for (int nn = 0; nn < 8; ++nn)
#pragma unroll
          for (int q = 0; q < 4; ++q) {
            int bq = ((l >> 4) << 2) + q;
            part[(((ks << 4) + bq) << 7) + (nn << 4) + lr16] = acc[nn][q];
          }
      } else {
        asm volatile("s_waitcnt vmcnt(0)" ::: "memory");  // xv ready (t==0 path)
      }
      __syncthreads();

      float hv, cv;
      unsigned short h16;
      {
        float gi = bf2f((unsigned short)(xv.x)), gf = bf2f((unsigned short)(xv.x >> 16));
        float gg = bf2f((unsigned short)(xv.y)), go = bf2f((unsigned short)(xv.y >> 16));
        if (t > 0) {
          float si = 0.f, sf = 0.f, sg = 0.f, so = 0.f;
#pragma unroll
          for (int ksx = 0; ksx < 8; ++ksx) {
            const float* p = part + (((ksx << 4) + b_l) << 7) + j;
            si += p[0]; sf += p[32]; sg += p[64]; so += p[96];
          }
          gi += si; gf += sf; gg += sg; go += so;
        }
        float iv = 1.f / (1.f + __expf(-gi));
        float fv = 1.f / (1.f + __expf(-gf));
        float gv = tanhf(gg);
        float ov = 1.f / (1.f + __expf(-go));
        cs = fv * cs + iv * gv;
        hv = ov * tanhf(cs);
        cv = cs;
        h16 = f2bf(hv);
        AS(hbuf + ((size_t)((t + 1) & 1) << 16) + ((size_t)b_g << 10) + hcol, h16);
      }
      asm volatile("s_waitcnt vmcnt(0)" ::: "memory");
      __syncthreads();
      if (tid == 0) AS(&gflags1[u], t + 1);

      outf[((((size_t)b_g << 9) + t) << 10) + hcol] = hv;
      if (t == 511) {
        hn[((size_t)b_g << 10) + hcol] = hv;
        cn[((size_t)b_g << 10) + hcol] = cv;
      } else {
        const int base = ks << 2;
        for (;;) {
          int f = (l < 4) ? AL(&gflags1[base + l]) : 0x7fffffff;
          if (__all(f > t)) break;
          __builtin_amdgcn_s_sleep(1);
        }
      }
    }
  }
}

// ---------------- fused: rec0+tail-producer (0..127) || rec1 (128..255) ------------
__global__ __launch_bounds__(512, 2) void k_fused(
    const unsigned short* __restrict__ xp0,
    const unsigned short* __restrict__ Whh0,
    unsigned short* __restrict__ hb0,
    int* __restrict__ flags0,
    unsigned short* __restrict__ out0,
    float* __restrict__ hn, float* __restrict__ cn,
    const unsigned short* __restrict__ Wih1,
    const float* __restrict__ bias1,
    const unsigned short* __restrict__ Whh1,
    unsigned short* __restrict__ xpp_all,
    unsigned short* __restrict__ hb1,
    int* __restrict__ flags1,
    int* __restrict__ fx,
    float* __restrict__ outf) {
  __shared__ float part[8 * 16 * 128];   // 64 KB
  __shared__ int gmin;                    // per-mb gate cache
  const int wg = blockIdx.x;
  if (wg < 128) {
    rec0_body(xp0, Whh0, hb0, flags0 + ((wg >> 5) << 8), out0, hn, cn,
              Wih1, bias1,
              xpp_all + ((size_t)wg << 18),
              &flags1[((wg >> 5) << 8) + (wg & 31)],
              &fx[wg],
              part, &gmin, wg & 31, wg >> 5);
  } else {
    const int w1 = wg - 128;
    layer1_body(out0, Wih1, bias1, Whh1,
                xpp_all + ((size_t)w1 << 18),
                hb1, flags0 + ((w1 >> 5) << 8), flags1 + ((w1 >> 5) << 8),
                &fx[w1],
                outf, hn + 65536, cn + 65536,
                part, &gmin, w1 & 31, w1 >> 5);
  }
}

// ---------------- launch ----------------
extern "C" void kernel_launch(void* const* d_in, const int* in_sizes, int n_in,
                              void* d_out, int out_size, void* d_ws, size_t ws_size,
                              hipStream_t stream) {
  (void)in_sizes; (void)n_in; (void)out_size; (void)ws_size;
  const float* x    = (const float*)d_in[0];
  const float* Wih0 = (const float*)d_in[1];
  const float* bih0 = (const float*)d_in[2];
  const float* Whh0 = (const float*)d_in[3];
  const float* bhh0 = (const float*)d_in[4];
  const float* Wih1 = (const float*)d_in[5];
  const float* bih1 = (const float*)d_in[6];
  const float* Whh1 = (const float*)d_in[7];
  const float* bhh1 = (const float*)d_in[8];
  float* dout = (float*)d_out;

  char* ws = (char*)d_ws;
  int*            flags0 = (int*)ws;                         // 4 KB
  int*            flags1 = (int*)(ws + 4096);                // 4 KB
  int*            fx     = (int*)(ws + 8192);                // 4 KB (128 used)
  unsigned short* hb0    = (unsigned short*)(ws + 12288);    // 256 KB
  unsigned short* hb1    = (unsigned short*)(ws + 274432);   // 256 KB
  float*          bias0  = (float*)(ws + 536576);            // 16 KB
  float*          bias1  = (float*)(ws + 552960);            // 16 KB
  unsigned short* wbf    = (unsigned short*)(ws + 569344);   // 32 MB: ih0,hh0,ih1,hh1
  unsigned short* xbf    = wbf + 16777216;                   // 64 MB (x bf16; reused as xpp)
  unsigned short* out0   = xbf + 33554432;                   // 64 MB
  unsigned short* xpb    = out0 + 33554432;                  // 256 MB (xp0)

  hipMemsetAsync(flags0, 0, 12288, stream);

  // merged prep: x cvt + 4 weight cvts + biases (one launch)
  k_prep<<<2048, 256, 0, stream>>>(x, Wih0, Whh0, Wih1, Whh1,
                                   bih0, bhh0, bih1, bhh1,
                                   xbf, wbf, bias0, bias1);

  float* hn = dout + 33554432;
  float* cn = dout + 33554432 + 131072;

  // layer 0 xp (serial; xbf becomes dead afterward and is reused as xpp)
  k_gemm<<<8192, 256, 0, stream>>>(xbf, wbf + 0, bias0, xpb, 0);

  // fused pipeline: rec0 (+ tail gemm producer) || rec1 (mb-paced gemm)
  k_fused<<<256, 512, 0, stream>>>(xpb, wbf + 4194304, hb0, flags0,
                                   out0, hn, cn,
                                   wbf + 8388608, bias1, wbf + 12582912,
                                   xbf, hb1, flags1, fx, dout);
}

// Round 19
// 4026.996 us; speedup vs baseline: 1.0912x; 1.0090x over previous
//
#include <hip/hip_runtime.h>
#include <stdint.h>

typedef __attribute__((ext_vector_type(8))) short short8;
typedef __attribute__((ext_vector_type(4))) float f32x4;

#define MFMA16(a, b, c) __builtin_amdgcn_mfma_f32_16x16x32_bf16((a), (b), (c), 0, 0, 0)
#define AL(p) __hip_atomic_load((p), __ATOMIC_RELAXED, __HIP_MEMORY_SCOPE_AGENT)
#define AS(p, v) __hip_atomic_store((p), (v), __ATOMIC_RELAXED, __HIP_MEMORY_SCOPE_AGENT)

__device__ __forceinline__ unsigned short f2bf(float f) {
  unsigned u = __float_as_uint(f);
  u = (u + 0x7FFFu + ((u >> 16) & 1u)) >> 16;   // RNE
  return (unsigned short)u;
}
__device__ __forceinline__ float bf2f(unsigned short u) {
  return __uint_as_float(((unsigned)u) << 16);
}

// ---------------- prep: single merged kernel (x cvt + 4 weight cvts + biases) -------
__global__ void k_prep(const float* __restrict__ x,
                       const float* __restrict__ w0, const float* __restrict__ w1,
                       const float* __restrict__ w2, const float* __restrict__ w3,
                       const float* __restrict__ a0, const float* __restrict__ b0,
                       const float* __restrict__ a1, const float* __restrict__ b1,
                       unsigned short* __restrict__ xbf,
                       unsigned short* __restrict__ wbf,
                       float* __restrict__ bias0, float* __restrict__ bias1) {
  const int gid = blockIdx.x * blockDim.x + threadIdx.x;
  const int stride = gridDim.x * blockDim.x;
  for (int i = gid; i < 8192; i += stride) {
    if (i < 4096) bias0[i] = a0[i] + b0[i];
    else          bias1[i - 4096] = a1[i - 4096] + b1[i - 4096];
  }
  for (int i = gid; i < 8388608; i += stride) {
    float4 v = reinterpret_cast<const float4*>(x)[i];
    ushort4 o;
    o.x = f2bf(v.x); o.y = f2bf(v.y); o.z = f2bf(v.z); o.w = f2bf(v.w);
    reinterpret_cast<ushort4*>(xbf)[i] = o;
  }
  for (int i = gid; i < 4194304; i += stride) {
    const float* sp = (i < 1048576) ? w0 : (i < 2097152) ? w1
                     : (i < 3145728) ? w2 : w3;
    float4 v = reinterpret_cast<const float4*>(sp)[i & 1048575];
    ushort4 o;
    o.x = f2bf(v.x); o.y = f2bf(v.y); o.z = f2bf(v.z); o.w = f2bf(v.w);
    reinterpret_cast<ushort4*>(wbf)[i] = o;
  }
}

// ---------------- xp GEMM (layer0): GATE-SPANNING tiles + LDS-transpose epilogue ----
// Tile = 128 rows x {gate*1024 + jc0+jl : 4 gates x 32 jl}. Output per row is a
// CONTIGUOUS 128-ushort span at (jc0*4) -> coalesced 16B stores via trs LDS.
__global__ __launch_bounds__(256) void k_gemm(
    const unsigned short* __restrict__ A,
    const unsigned short* __restrict__ W,
    const float* __restrict__ bias,
    unsigned short* __restrict__ out,
    int mode) {
  __shared__ unsigned short trs[128 * 128];   // 32 KB
  const int tid = threadIdx.x, l = tid & 63, wv = tid >> 6;
  const int wm = wv >> 1, wn = wv & 1;
  const int tm = blockIdx.x >> 5, tn = blockIdx.x & 31;
  const int m_base = tm * 128 + wm * 64;
  const int jc0 = tn << 5;                    // 32 jc per tile
  const int lr = l & 15, k8 = (l >> 4) << 3;

  size_t a_off[4], b_off[4];
#pragma unroll
  for (int i = 0; i < 4; ++i) {
    int r = m_base + i * 16 + lr;
    int ar = mode ? r : (((r & 63) << 9) + (r >> 6));
    a_off[i] = ((size_t)ar << 10) + k8;
    int ct = (wn << 6) + i * 16 + lr;         // col-in-tile 0..127
    int wrow = ((ct >> 5) << 10) + jc0 + (ct & 31);
    b_off[i] = ((size_t)wrow << 10) + k8;
  }
  f32x4 acc[4][4] = {};
#pragma unroll 2
  for (int k0 = 0; k0 < 1024; k0 += 32) {
    short8 a[4], b[4];
#pragma unroll
    for (int i = 0; i < 4; ++i) a[i] = *reinterpret_cast<const short8*>(A + a_off[i] + k0);
#pragma unroll
    for (int j = 0; j < 4; ++j) b[j] = *reinterpret_cast<const short8*>(W + b_off[j] + k0);
#pragma unroll
    for (int i = 0; i < 4; ++i)
#pragma unroll
      for (int j = 0; j < 4; ++j) acc[i][j] = MFMA16(a[i], b[j], acc[i][j]);
  }
  // epilogue: acc -> trs (interleaved within-tile layout), then coalesced stores
  const int oq = (l >> 4) << 2, oc = l & 15;
#pragma unroll
  for (int j = 0; j < 4; ++j) {
    int ct = (wn << 6) + j * 16 + oc;
    int gate = ct >> 5, jl = ct & 31;
    float bs = bias[(gate << 10) + jc0 + jl];
#pragma unroll
    for (int i = 0; i < 4; ++i) {
      int rt = (wm << 6) + i * 16 + oq;
#pragma unroll
      for (int q = 0; q < 4; ++q)
        trs[((rt + q) << 7) + (jl << 2) + gate] = f2bf(acc[i][j][q] + bs);
    }
  }
  __syncthreads();
#pragma unroll
  for (int s = 0; s < 8; ++s) {
    int ch = tid + (s << 8);                  // 2048 chunks of 8 ushorts
    int row = ch >> 4, off16 = (ch & 15) << 3;
    short8 v = *reinterpret_cast<const short8*>(trs + (ch << 3));
    *reinterpret_cast<short8*>(
        out + (((size_t)(m_base - (wm << 6) + row)) << 12) + (jc0 << 2) + off16) = v;
  }
}

// ---------------- shared: one xp1 chunk gemm with PER-MB producer gating ------------
__device__ __forceinline__ void gemm_chunk(
    const unsigned short* __restrict__ out0,
    const unsigned short* __restrict__ Wih1,
    const float* __restrict__ bias1,
    unsigned short* __restrict__ xb,
    const int* __restrict__ gf0,
    int* __restrict__ gmin_lds,
    char* smem, int g, int hc0, int c,
    int tid, int l, int ks, int lr16, int k8) {
  const int cg = (ks << 4) + lr16;
  const int gate = cg >> 5, jl = cg & 31;
  const int wrow = (gate << 10) + hc0 + jl;
  const float bsv = bias1[wrow];
  unsigned short* trs = (unsigned short*)smem;   // first 16 KB, reused post-MFMA

  int gmin = 0;
  for (int mb = 0; mb < 16; ++mb) {
    // ---- per-mb producer gate ----
    const int thr = (c << 6) + (mb << 2) + 5;
    if (gmin < thr) {
      if (tid == 0) {
        int m;
        for (;;) {
          m = 0x7fffffff;
          for (int i = 0; i < 32; ++i) { int f = AL(&gf0[i]); m = (f < m) ? f : m; }
          if (m >= thr) break;
          __builtin_amdgcn_s_sleep(4);
        }
        *gmin_lds = m;
      }
      __syncthreads();
      gmin = *gmin_lds;
    }

    f32x4 acc[4] = {{0.f,0.f,0.f,0.f},{0.f,0.f,0.f,0.f},{0.f,0.f,0.f,0.f},{0.f,0.f,0.f,0.f}};
#pragma unroll 1
    for (int kh = 0; kh < 2; ++kh) {
      short8 st[8];
#pragma unroll
      for (int s = 0; s < 8; ++s) {
        int ch = tid + (s << 9);
        int row = ch >> 6, kc = ch & 63;
        int t = (c << 6) + (mb << 2) + (row >> 4);
        int b = (g << 4) + (row & 15);
        st[s] = *reinterpret_cast<const short8*>(
            out0 + (((size_t)((t << 6) + b)) << 10) + (kh << 9) + (kc << 3));
      }
#pragma unroll
      for (int s = 0; s < 8; ++s) {
        int ch = tid + (s << 9);
        int row = ch >> 6, kc = ch & 63;
        *reinterpret_cast<short8*>(smem + (row << 10) + ((kc ^ (row & 7)) << 4)) = st[s];
      }
      __syncthreads();
#pragma unroll
      for (int kk = 0; kk < 16; ++kk) {
        short8 bfr = *reinterpret_cast<const short8*>(
            Wih1 + ((size_t)wrow << 10) + (kh << 9) + (kk << 5) + k8);
        int kc = (kk << 2) + (k8 >> 3);
#pragma unroll
        for (int mt = 0; mt < 4; ++mt) {
          int row = (mt << 4) + lr16;
          short8 a = *reinterpret_cast<const short8*>(
              smem + (row << 10) + ((kc ^ (row & 7)) << 4));
          acc[mt] = MFMA16(a, bfr, acc[mt]);
        }
      }
      __syncthreads();
    }
    // transpose to interleaved layout in LDS, then 16B sc1 stores
#pragma unroll
    for (int mt = 0; mt < 4; ++mt)
#pragma unroll
      for (int q = 0; q < 4; ++q) {
        int bi = ((l >> 4) << 2) + q;
        trs[(((mt << 4) + bi) << 7) + (jl << 2) + gate] = f2bf(acc[mt][q] + bsv);
      }
    __syncthreads();
#pragma unroll
    for (int s = 0; s < 2; ++s) {
      int ch = (tid << 1) + s;
      short8 v = *reinterpret_cast<const short8*>(trs + (ch << 3));
      unsigned short* dst = xb + (mb << 13) + (ch << 3);
      asm volatile("global_store_dwordx4 %0, %1, off sc0 sc1"
                   :: "v"(dst), "v"(v) : "memory");
    }
    __syncthreads();
  }
  asm volatile("s_waitcnt vmcnt(0)" ::: "memory");
  __syncthreads();
}

// ---------------- layer-0 recurrence + tail producer for partner chunks 5..7 ------
__device__ __forceinline__ void rec0_body(
    const unsigned short* __restrict__ xp,
    const unsigned short* __restrict__ Whh,
    unsigned short* __restrict__ hbuf,
    int* __restrict__ gflags,
    unsigned short* __restrict__ out_bf,
    float* __restrict__ hn, float* __restrict__ cn,
    const unsigned short* __restrict__ Wih1,
    const float* __restrict__ bias1,
    unsigned short* __restrict__ xpp_partner,
    const int* __restrict__ pflag1,
    int* __restrict__ fx_self,
    float* part, int* gmin_lds, int w, int g) {
  const int tid = threadIdx.x;
  const int l = tid & 63, ks = tid >> 6;
  const int hc0 = w << 5;
  const int lr16 = l & 15, k8 = (l >> 4) << 3;

  short8 bf[8][4];
#pragma unroll
  for (int nn = 0; nn < 8; ++nn) {
    const int c_wg = (nn << 4) + lr16;
    const unsigned short* wp =
        Whh + ((size_t)(((c_wg >> 5) << 10) + hc0 + (c_wg & 31)) << 10) + (ks << 7) + k8;
#pragma unroll
    for (int kk = 0; kk < 4; ++kk)
      bf[nn][kk] = *reinterpret_cast<const short8*>(wp + (kk << 5));
  }

  const int arow = (g << 4) + lr16;
  const size_t aoff = ((size_t)arow << 10) + (ks << 7) + k8;

  const int b_l = tid >> 5;
  const int j = tid & 31;
  const int b_g = (g << 4) + b_l;
  const int hcol = hc0 + j;

  float cs = 0.f;

  auto xload = [&](int t) -> uint2 {
    return *reinterpret_cast<const uint2*>(
        xp + (((size_t)((t << 6) + b_g)) << 12) + (hcol << 2));
  };

  auto step = [&](int t, uint2 xv) {
    if (t > 0) {
      const unsigned short* ab = hbuf + ((size_t)(t & 1) << 16) + aoff;
      short8 av[4];
#pragma unroll
      for (int kk = 0; kk < 4; ++kk) {
        const unsigned short* p = ab + (kk << 5);
        asm volatile("global_load_dwordx4 %0, %1, off sc0 sc1"
                     : "=v"(av[kk]) : "v"(p) : "memory");
      }
      asm volatile("s_waitcnt vmcnt(0)" ::: "memory");
      __builtin_amdgcn_sched_barrier(0);
      f32x4 acc[8] = {{0.f,0.f,0.f,0.f},{0.f,0.f,0.f,0.f},{0.f,0.f,0.f,0.f},{0.f,0.f,0.f,0.f},
                      {0.f,0.f,0.f,0.f},{0.f,0.f,0.f,0.f},{0.f,0.f,0.f,0.f},{0.f,0.f,0.f,0.f}};
#pragma unroll
      for (int kk = 0; kk < 4; ++kk)
#pragma unroll
        for (int nn = 0; nn < 8; ++nn)
          acc[nn] = MFMA16(av[kk], bf[nn][kk], acc[nn]);
#pragma unroll
      for (int nn = 0; nn < 8; ++nn)
#pragma unroll
        for (int q = 0; q < 4; ++q) {
          int bq = ((l >> 4) << 2) + q;
          part[(((ks << 4) + bq) << 7) + (nn << 4) + lr16] = acc[nn][q];
        }
    }
    __syncthreads();

    float hv, cv;
    unsigned short h16;
    {
      float gi = bf2f((unsigned short)(xv.x)), gf = bf2f((unsigned short)(xv.x >> 16));
      float gg = bf2f((unsigned short)(xv.y)), go = bf2f((unsigned short)(xv.y >> 16));
      if (t > 0) {
        float si = 0.f, sf = 0.f, sg = 0.f, so = 0.f;
#pragma unroll
        for (int ksx = 0; ksx < 8; ++ksx) {
          const float* p = part + (((ksx << 4) + b_l) << 7) + j;
          si += p[0]; sf += p[32]; sg += p[64]; so += p[96];
        }
        gi += si; gf += sf; gg += sg; go += so;
      }
      float iv = 1.f / (1.f + __expf(-gi));
      float fv = 1.f / (1.f + __expf(-gf));
      float gv = tanhf(gg);
      float ov = 1.f / (1.f + __expf(-go));
      cs = fv * cs + iv * gv;
      hv = ov * tanhf(cs);
      cv = cs;
      h16 = f2bf(hv);
      AS(hbuf + ((size_t)((t + 1) & 1) << 16) + ((size_t)b_g << 10) + hcol, h16);
    }
    asm volatile("s_waitcnt vmcnt(0)" ::: "memory");
    __syncthreads();
    if (tid == 0) AS(&gflags[w], t + 1);

    AS(out_bf + ((((size_t)t << 6) + b_g) << 10) + hcol, h16);
    if (t == 511) {
      hn[((size_t)b_g << 10) + hcol] = hv;
      cn[((size_t)b_g << 10) + hcol] = cv;
    } else {
      const int base = ks << 2;
      for (;;) {
        int f = (l < 4) ? AL(&gflags[base + l]) : 0x7fffffff;
        if (__all(f > t)) break;
        __builtin_amdgcn_s_sleep(1);
      }
    }
  };

  uint2 zz = {0u, 0u};
  uint2 xA[4] = {zz, zz, zz, zz}, xB[4] = {zz, zz, zz, zz};
#pragma unroll
  for (int s = 0; s < 4; ++s) xA[s] = xload(s);
  for (int tc = 0; tc < 512; tc += 8) {
#pragma unroll
    for (int s = 0; s < 4; ++s) xB[s] = xload(tc + 4 + s);
#pragma unroll
    for (int s = 0; s < 4; ++s) step(tc + s, xA[s]);
    if (tc + 8 < 512) {
#pragma unroll
      for (int s = 0; s < 4; ++s) xA[s] = xload(tc + 8 + s);
    }
#pragma unroll
    for (int s = 0; s < 4; ++s) step(tc + 4 + s, xB[s]);
  }

  asm volatile("s_waitcnt vmcnt(0)" ::: "memory");
  __syncthreads();
  if (tid == 0) AS(&gflags[w], 1000);

  // ---- tail producer: partner rec1 WG's xp1 chunks 5..7 ----
  if (tid == 0) {
    for (;;) {
      bool ok = true;
      for (int i = 0; i < 32; ++i)
        if (AL(&gflags[i]) < 1000) { ok = false; break; }
      if (ok) break;
      __builtin_amdgcn_s_sleep(16);
    }
  }
  __syncthreads();
  for (int c = 5; c < 8; ++c) {
    const int need = (c - 1) << 6;
    if (tid == 0) {
      while (AL(pflag1) < need) __builtin_amdgcn_s_sleep(16);
    }
    __syncthreads();
    gemm_chunk(out_bf, Wih1, bias1,
               xpp_partner + ((size_t)(c & 1) << 17),
               gflags, gmin_lds,
               (char*)part, g, hc0, c, tid, l, ks, lr16, k8);
    if (tid == 0) AS(fx_self, c + 1);
  }
}

// ---------------- layer-1: chunks 0..4 self-gemm (mb-paced), 5..7 from partner ------
__device__ __forceinline__ void layer1_body(
    const unsigned short* __restrict__ out0,
    const unsigned short* __restrict__ Wih1,
    const float* __restrict__ bias1,
    const unsigned short* __restrict__ Whh1,
    unsigned short* __restrict__ xpp,      // private 2 x 131072 ushorts (ping-pong, sc1)
    unsigned short* __restrict__ hbuf,
    int* __restrict__ gflags0,
    int* __restrict__ gflags1,
    const int* __restrict__ fx_self,
    float* __restrict__ outf,
    float* __restrict__ hn, float* __restrict__ cn,
    float* part, int* gmin_lds, int u, int g) {
  const int tid = threadIdx.x;
  const int l = tid & 63, ks = tid >> 6;
  const int hc0 = u << 5;
  const int lr16 = l & 15, k8 = (l >> 4) << 3;

  short8 bf[8][4];
#pragma unroll
  for (int nn = 0; nn < 8; ++nn) {
    const int c_wg = (nn << 4) + lr16;
    const unsigned short* wp =
        Whh1 + ((size_t)(((c_wg >> 5) << 10) + hc0 + (c_wg & 31)) << 10) + (ks << 7) + k8;
#pragma unroll
    for (int kk = 0; kk < 4; ++kk)
      bf[nn][kk] = *reinterpret_cast<const short8*>(wp + (kk << 5));
  }

  const int arow = (g << 4) + lr16;
  const size_t aoff = ((size_t)arow << 10) + (ks << 7) + k8;
  const int b_l = tid >> 5, j = tid & 31;
  const int b_g = (g << 4) + b_l;
  const int hcol = hc0 + j;

  float cs = 0.f;

  for (int c = 0; c < 8; ++c) {
    if (c < 5) {
      gemm_chunk(out0, Wih1, bias1,
                 xpp + ((size_t)(c & 1) << 17),
                 gflags0, gmin_lds,
                 (char*)part, g, hc0, c, tid, l, ks, lr16, k8);
    } else {
      if (tid == 0) {
        while (AL(fx_self) < c + 1) __builtin_amdgcn_s_sleep(16);
      }
      __syncthreads();
    }

    const unsigned short* xb = xpp + ((size_t)(c & 1) << 17);
    for (int ti = 0; ti < 64; ++ti) {
      const int t = (c << 6) + ti;
      uint2 xv;
      {
        const unsigned short* p = xb + (((ti << 4) + b_l) << 7) + (j << 2);
        asm volatile("global_load_dwordx2 %0, %1, off sc0 sc1"
                     : "=v"(xv) : "v"(p) : "memory");
      }

      if (t > 0) {
        const unsigned short* ab = hbuf + ((size_t)(t & 1) << 16) + aoff;
        short8 av[4];
#pragma unroll
        for (int kk = 0; kk < 4; ++kk) {
          const unsigned short* p = ab + (kk << 5);
          asm volatile("global_load_dwordx4 %0, %1, off sc0 sc1"
                       : "=v"(av[kk]) : "v"(p) : "memory");
        }
        asm volatile("s_waitcnt vmcnt(0)" ::: "memory");
        __builtin_amdgcn_sched_barrier(0);
        f32x4 acc[8] = {{0.f,0.f,0.f,0.f},{0.f,0.f,0.f,0.f},{0.f,0.f,0.f,0.f},{0.f,0.f,0.f,0.f},
                        {0.f,0.f,0.f,0.f},{0.f,0.f,0.f,0.f},{0.f,0.f,0.f,0.f},{0.f,0.f,0.f,0.f}};
#pragma unroll
        for (int kk = 0; kk < 4; ++kk)
#pragma unroll
          for (int nn = 0; nn < 8; ++nn)
            acc[nn] = MFMA16(av[kk], bf[nn][kk], acc[nn]);
#pragma unroll
        for (int nn = 0; nn < 8; ++nn)
#pragma unroll
          for (int q = 0; q < 4; ++q) {
            int bq = ((l >> 4) << 2) + q;
            part[(((ks << 4) + bq) << 7) + (nn << 4) + lr16] = acc[nn][q];
          }
      } else {
        asm volatile("s_waitcnt vmcnt(0)" ::: "memory");  // xv ready (t==0 path)
      }
      __syncthreads();

      float hv, cv;
      unsigned short h16;
      {
        float gi = bf2f((unsigned short)(xv.x)), gf = bf2f((unsigned short)(xv.x >> 16));
        float gg = bf2f((unsigned short)(xv.y)), go = bf2f((unsigned short)(xv.y >> 16));
        if (t > 0) {
          float si = 0.f, sf = 0.f, sg = 0.f, so = 0.f;
#pragma unroll
          for (int ksx = 0; ksx < 8; ++ksx) {
            const float* p = part + (((ksx << 4) + b_l) << 7) + j;
            si += p[0]; sf += p[32]; sg += p[64]; so += p[96];
          }
          gi += si; gf += sf; gg += sg; go += so;
        }
        float iv = 1.f / (1.f + __expf(-gi));
        float fv = 1.f / (1.f + __expf(-gf));
        float gv = tanhf(gg);
        float ov = 1.f / (1.f + __expf(-go));
        cs = fv * cs + iv * gv;
        hv = ov * tanhf(cs);
        cv = cs;
        h16 = f2bf(hv);
        AS(hbuf + ((size_t)((t + 1) & 1) << 16) + ((size_t)b_g << 10) + hcol, h16);
      }
      asm volatile("s_waitcnt vmcnt(0)" ::: "memory");
      __syncthreads();
      if (tid == 0) AS(&gflags1[u], t + 1);

      outf[((((size_t)b_g << 9) + t) << 10) + hcol] = hv;
      if (t == 511) {
        hn[((size_t)b_g << 10) + hcol] = hv;
        cn[((size_t)b_g << 10) + hcol] = cv;
      } else {
        const int base = ks << 2;
        for (;;) {
          int f = (l < 4) ? AL(&gflags1[base + l]) : 0x7fffffff;
          if (__all(f > t)) break;
          __builtin_amdgcn_s_sleep(1);
        }
      }
    }
  }
}

// ---------------- fused: rec0+tail-producer (0..127) || rec1 (128..255) ------------
__global__ __launch_bounds__(512, 2) void k_fused(
    const unsigned short* __restrict__ xp0,
    const unsigned short* __restrict__ Whh0,
    unsigned short* __restrict__ hb0,
    int* __restrict__ flags0,
    unsigned short* __restrict__ out0,
    float* __restrict__ hn, float* __restrict__ cn,
    const unsigned short* __restrict__ Wih1,
    const float* __restrict__ bias1,
    const unsigned short* __restrict__ Whh1,
    unsigned short* __restrict__ xpp_all,
    unsigned short* __restrict__ hb1,
    int* __restrict__ flags1,
    int* __restrict__ fx,
    float* __restrict__ outf) {
  __shared__ float part[8 * 16 * 128];   // 64 KB
  __shared__ int gmin;                    // per-mb gate cache
  const int wg = blockIdx.x;
  if (wg < 128) {
    rec0_body(xp0, Whh0, hb0, flags0 + ((wg >> 5) << 8), out0, hn, cn,
              Wih1, bias1,
              xpp_all + ((size_t)wg << 18),
              &flags1[((wg >> 5) << 8) + (wg & 31)],
              &fx[wg],
              part, &gmin, wg & 31, wg >> 5);
  } else {
    const int w1 = wg - 128;
    layer1_body(out0, Wih1, bias1, Whh1,
                xpp_all + ((size_t)w1 << 18),
                hb1, flags0 + ((w1 >> 5) << 8), flags1 + ((w1 >> 5) << 8),
                &fx[w1],
                outf, hn + 65536, cn + 65536,
                part, &gmin, w1 & 31, w1 >> 5);
  }
}

// ---------------- launch ----------------
extern "C" void kernel_launch(void* const* d_in, const int* in_sizes, int n_in,
                              void* d_out, int out_size, void* d_ws, size_t ws_size,
                              hipStream_t stream) {
  (void)in_sizes; (void)n_in; (void)out_size; (void)ws_size;
  const float* x    = (const float*)d_in[0];
  const float* Wih0 = (const float*)d_in[1];
  const float* bih0 = (const float*)d_in[2];
  const float* Whh0 = (const float*)d_in[3];
  const float* bhh0 = (const float*)d_in[4];
  const float* Wih1 = (const float*)d_in[5];
  const float* bih1 = (const float*)d_in[6];
  const float* Whh1 = (const float*)d_in[7];
  const float* bhh1 = (const float*)d_in[8];
  float* dout = (float*)d_out;

  char* ws = (char*)d_ws;
  int*            flags0 = (int*)ws;                         // 4 KB
  int*            flags1 = (int*)(ws + 4096);                // 4 KB
  int*            fx     = (int*)(ws + 8192);                // 4 KB (128 used)
  unsigned short* hb0    = (unsigned short*)(ws + 12288);    // 256 KB
  unsigned short* hb1    = (unsigned short*)(ws + 274432);   // 256 KB
  float*          bias0  = (float*)(ws + 536576);            // 16 KB
  float*          bias1  = (float*)(ws + 552960);            // 16 KB
  unsigned short* wbf    = (unsigned short*)(ws + 569344);   // 32 MB: ih0,hh0,ih1,hh1
  unsigned short* xbf    = wbf + 16777216;                   // 64 MB (x bf16; reused as xpp)
  unsigned short* out0   = xbf + 33554432;                   // 64 MB
  unsigned short* xpb    = out0 + 33554432;                  // 256 MB (xp0)

  hipMemsetAsync(flags0, 0, 12288, stream);

  // merged prep: x cvt + 4 weight cvts + biases (one launch)
  k_prep<<<2048, 256, 0, stream>>>(x, Wih0, Whh0, Wih1, Whh1,
                                   bih0, bhh0, bih1, bhh1,
                                   xbf, wbf, bias0, bias1);

  float* hn = dout + 33554432;
  float* cn = dout + 33554432 + 131072;

  // layer 0 xp (serial; xbf becomes dead afterward and is reused as xpp)
  k_gemm<<<8192, 256, 0, stream>>>(xbf, wbf + 0, bias0, xpb, 0);

  // fused pipeline: rec0 (+ tail gemm producer) || rec1 (mb-paced gemm)
  k_fused<<<256, 512, 0, stream>>>(xpb, wbf + 4194304, hb0, flags0,
                                   out0, hn, cn,
                                   wbf + 8388608, bias1, wbf + 12582912,
                                   xbf, hb1, flags1, fx, dout);
}

// Round 20
// 3521.331 us; speedup vs baseline: 1.2479x; 1.1436x over previous
//
#include <hip/hip_runtime.h>
#include <stdint.h>

typedef __attribute__((ext_vector_type(8))) short short8;
typedef __attribute__((ext_vector_type(4))) float f32x4;

#define MFMA16(a, b, c) __builtin_amdgcn_mfma_f32_16x16x32_bf16((a), (b), (c), 0, 0, 0)
#define AL(p) __hip_atomic_load((p), __ATOMIC_RELAXED, __HIP_MEMORY_SCOPE_AGENT)
#define AS(p, v) __hip_atomic_store((p), (v), __ATOMIC_RELAXED, __HIP_MEMORY_SCOPE_AGENT)

__device__ __forceinline__ unsigned short f2bf(float f) {
  unsigned u = __float_as_uint(f);
  u = (u + 0x7FFFu + ((u >> 16) & 1u)) >> 16;   // RNE
  return (unsigned short)u;
}
__device__ __forceinline__ float bf2f(unsigned short u) {
  return __uint_as_float(((unsigned)u) << 16);
}

// ---------------- prep: single merged kernel (x cvt + 4 weight cvts + biases) -------
__global__ void k_prep(const float* __restrict__ x,
                       const float* __restrict__ w0, const float* __restrict__ w1,
                       const float* __restrict__ w2, const float* __restrict__ w3,
                       const float* __restrict__ a0, const float* __restrict__ b0,
                       const float* __restrict__ a1, const float* __restrict__ b1,
                       unsigned short* __restrict__ xbf,
                       unsigned short* __restrict__ wbf,
                       float* __restrict__ bias0, float* __restrict__ bias1) {
  const int gid = blockIdx.x * blockDim.x + threadIdx.x;
  const int stride = gridDim.x * blockDim.x;
  for (int i = gid; i < 8192; i += stride) {
    if (i < 4096) bias0[i] = a0[i] + b0[i];
    else          bias1[i - 4096] = a1[i - 4096] + b1[i - 4096];
  }
  for (int i = gid; i < 8388608; i += stride) {
    float4 v = reinterpret_cast<const float4*>(x)[i];
    ushort4 o;
    o.x = f2bf(v.x); o.y = f2bf(v.y); o.z = f2bf(v.z); o.w = f2bf(v.w);
    reinterpret_cast<ushort4*>(xbf)[i] = o;
  }
  for (int i = gid; i < 4194304; i += stride) {
    const float* sp = (i < 1048576) ? w0 : (i < 2097152) ? w1
                     : (i < 3145728) ? w2 : w3;
    float4 v = reinterpret_cast<const float4*>(sp)[i & 1048575];
    ushort4 o;
    o.x = f2bf(v.x); o.y = f2bf(v.y); o.z = f2bf(v.z); o.w = f2bf(v.w);
    reinterpret_cast<ushort4*>(wbf)[i] = o;
  }
}

// ---------------- xp GEMM (layer0): LDS-STAGED (R20) ---------------------------------
// 128x128 gate-spanning tiles; 16 K-tiles of BK=64. A/B staged into 32 KB LDS via
// plain short8 loads + XOR-swizzled writes (chunk ^= row&7); 2 barriers/tile;
// 32 MFMA/tile from LDS. Epilogue reuses LDS as trs transpose buffer (R19 proven).
__global__ __launch_bounds__(256) void k_gemm(
    const unsigned short* __restrict__ A,
    const unsigned short* __restrict__ W,
    const float* __restrict__ bias,
    unsigned short* __restrict__ out,
    int mode) {
  __shared__ char smem[32768];            // bufA 16K | bufB 16K ; epilogue: trs 32K
  unsigned short* trs = (unsigned short*)smem;
  char* bufA = smem;
  char* bufB = smem + 16384;

  const int tid = threadIdx.x, l = tid & 63, wv = tid >> 6;
  const int wm = wv >> 1, wn = wv & 1;
  const int tm = blockIdx.x >> 5, tn = blockIdx.x & 31;
  const int mb0 = tm << 7;
  const int jc0 = tn << 5;
  const int lr = l & 15;
  const int c4 = l >> 4;                  // 0..3: 16B-chunk offset within a K32 group

  // staging: thread covers chunks ch = tid + s*256 (s=0..3) of each 1024-chunk tile
  size_t sgA[4], sgB[4];
  int slds[4];
#pragma unroll
  for (int s = 0; s < 4; ++s) {
    int ch = tid + (s << 8);
    int row = ch >> 3, kc8 = ch & 7;
    int r = mb0 + row;
    int ar = mode ? r : (((r & 63) << 9) + (r >> 6));
    sgA[s] = ((size_t)ar << 10) + ((kc8 ^ (row & 7)) << 3);
    int wrow = ((row >> 5) << 10) + jc0 + (row & 31);
    sgB[s] = ((size_t)wrow << 10) + ((kc8 ^ (row & 7)) << 3);
    slds[s] = ch << 4;
  }

  f32x4 acc[4][4] = {};
  for (int k0 = 0; k0 < 1024; k0 += 64) {
    short8 stA[4], stB[4];
#pragma unroll
    for (int s = 0; s < 4; ++s) {
      stA[s] = *reinterpret_cast<const short8*>(A + sgA[s] + k0);
      stB[s] = *reinterpret_cast<const short8*>(W + sgB[s] + k0);
    }
#pragma unroll
    for (int s = 0; s < 4; ++s) {
      *reinterpret_cast<short8*>(bufA + slds[s]) = stA[s];
      *reinterpret_cast<short8*>(bufB + slds[s]) = stB[s];
    }
    __syncthreads();
#pragma unroll
    for (int kkk = 0; kkk < 2; ++kkk) {
      short8 a[4], b[4];
      const int c = (kkk << 2) + c4;
#pragma unroll
      for (int i = 0; i < 4; ++i) {
        int rt = (wm << 6) + (i << 4) + lr;
        a[i] = *reinterpret_cast<const short8*>(
            bufA + (rt << 7) + ((c ^ (rt & 7)) << 4));
        int ct = (wn << 6) + (i << 4) + lr;
        b[i] = *reinterpret_cast<const short8*>(
            bufB + (ct << 7) + ((c ^ (ct & 7)) << 4));
      }
#pragma unroll
      for (int i = 0; i < 4; ++i)
#pragma unroll
        for (int j = 0; j < 4; ++j)
          acc[i][j] = MFMA16(a[i], b[j], acc[i][j]);
    }
    __syncthreads();
  }

  // epilogue: acc -> trs (interleaved within-tile layout), then coalesced stores
  const int oq = (l >> 4) << 2, oc = l & 15;
#pragma unroll
  for (int j = 0; j < 4; ++j) {
    int ct = (wn << 6) + j * 16 + oc;
    int gate = ct >> 5, jl = ct & 31;
    float bs = bias[(gate << 10) + jc0 + jl];
#pragma unroll
    for (int i = 0; i < 4; ++i) {
      int rt = (wm << 6) + i * 16 + oq;
#pragma unroll
      for (int q = 0; q < 4; ++q)
        trs[((rt + q) << 7) + (jl << 2) + gate] = f2bf(acc[i][j][q] + bs);
    }
  }
  __syncthreads();
#pragma unroll
  for (int s = 0; s < 8; ++s) {
    int ch = tid + (s << 8);                  // 2048 chunks of 8 ushorts
    int row = ch >> 4, off16 = (ch & 15) << 3;
    short8 v = *reinterpret_cast<const short8*>(trs + (ch << 3));
    *reinterpret_cast<short8*>(
        out + (((size_t)(mb0 + row)) << 12) + (jc0 << 2) + off16) = v;
  }
}

// ---------------- shared: one xp1 chunk gemm with PER-MB producer gating ------------
__device__ __forceinline__ void gemm_chunk(
    const unsigned short* __restrict__ out0,
    const unsigned short* __restrict__ Wih1,
    const float* __restrict__ bias1,
    unsigned short* __restrict__ xb,
    const int* __restrict__ gf0,
    int* __restrict__ gmin_lds,
    char* smem, int g, int hc0, int c,
    int tid, int l, int ks, int lr16, int k8) {
  const int cg = (ks << 4) + lr16;
  const int gate = cg >> 5, jl = cg & 31;
  const int wrow = (gate << 10) + hc0 + jl;
  const float bsv = bias1[wrow];
  unsigned short* trs = (unsigned short*)smem;   // first 16 KB, reused post-MFMA

  int gmin = 0;
  for (int mb = 0; mb < 16; ++mb) {
    // ---- per-mb producer gate ----
    const int thr = (c << 6) + (mb << 2) + 5;
    if (gmin < thr) {
      if (tid == 0) {
        int m;
        for (;;) {
          m = 0x7fffffff;
          for (int i = 0; i < 32; ++i) { int f = AL(&gf0[i]); m = (f < m) ? f : m; }
          if (m >= thr) break;
          __builtin_amdgcn_s_sleep(4);
        }
        *gmin_lds = m;
      }
      __syncthreads();
      gmin = *gmin_lds;
    }

    f32x4 acc[4] = {{0.f,0.f,0.f,0.f},{0.f,0.f,0.f,0.f},{0.f,0.f,0.f,0.f},{0.f,0.f,0.f,0.f}};
#pragma unroll 1
    for (int kh = 0; kh < 2; ++kh) {
      short8 st[8];
#pragma unroll
      for (int s = 0; s < 8; ++s) {
        int ch = tid + (s << 9);
        int row = ch >> 6, kc = ch & 63;
        int t = (c << 6) + (mb << 2) + (row >> 4);
        int b = (g << 4) + (row & 15);
        st[s] = *reinterpret_cast<const short8*>(
            out0 + (((size_t)((t << 6) + b)) << 10) + (kh << 9) + (kc << 3));
      }
#pragma unroll
      for (int s = 0; s < 8; ++s) {
        int ch = tid + (s << 9);
        int row = ch >> 6, kc = ch & 63;
        *reinterpret_cast<short8*>(smem + (row << 10) + ((kc ^ (row & 7)) << 4)) = st[s];
      }
      __syncthreads();
#pragma unroll
      for (int kk = 0; kk < 16; ++kk) {
        short8 bfr = *reinterpret_cast<const short8*>(
            Wih1 + ((size_t)wrow << 10) + (kh << 9) + (kk << 5) + k8);
        int kc = (kk << 2) + (k8 >> 3);
#pragma unroll
        for (int mt = 0; mt < 4; ++mt) {
          int row = (mt << 4) + lr16;
          short8 a = *reinterpret_cast<const short8*>(
              smem + (row << 10) + ((kc ^ (row & 7)) << 4));
          acc[mt] = MFMA16(a, bfr, acc[mt]);
        }
      }
      __syncthreads();
    }
    // transpose to interleaved layout in LDS, then 16B sc1 stores
#pragma unroll
    for (int mt = 0; mt < 4; ++mt)
#pragma unroll
      for (int q = 0; q < 4; ++q) {
        int bi = ((l >> 4) << 2) + q;
        trs[(((mt << 4) + bi) << 7) + (jl << 2) + gate] = f2bf(acc[mt][q] + bsv);
      }
    __syncthreads();
#pragma unroll
    for (int s = 0; s < 2; ++s) {
      int ch = (tid << 1) + s;
      short8 v = *reinterpret_cast<const short8*>(trs + (ch << 3));
      unsigned short* dst = xb + (mb << 13) + (ch << 3);
      asm volatile("global_store_dwordx4 %0, %1, off sc0 sc1"
                   :: "v"(dst), "v"(v) : "memory");
    }
    __syncthreads();
  }
  asm volatile("s_waitcnt vmcnt(0)" ::: "memory");
  __syncthreads();
}

// ---------------- layer-0 recurrence + tail producer for partner chunks 5..7 ------
__device__ __forceinline__ void rec0_body(
    const unsigned short* __restrict__ xp,
    const unsigned short* __restrict__ Whh,
    unsigned short* __restrict__ hbuf,
    int* __restrict__ gflags,
    unsigned short* __restrict__ out_bf,
    float* __restrict__ hn, float* __restrict__ cn,
    const unsigned short* __restrict__ Wih1,
    const float* __restrict__ bias1,
    unsigned short* __restrict__ xpp_partner,
    const int* __restrict__ pflag1,
    int* __restrict__ fx_self,
    float* part, int* gmin_lds, int w, int g) {
  const int tid = threadIdx.x;
  const int l = tid & 63, ks = tid >> 6;
  const int hc0 = w << 5;
  const int lr16 = l & 15, k8 = (l >> 4) << 3;

  short8 bf[8][4];
#pragma unroll
  for (int nn = 0; nn < 8; ++nn) {
    const int c_wg = (nn << 4) + lr16;
    const unsigned short* wp =
        Whh + ((size_t)(((c_wg >> 5) << 10) + hc0 + (c_wg & 31)) << 10) + (ks << 7) + k8;
#pragma unroll
    for (int kk = 0; kk < 4; ++kk)
      bf[nn][kk] = *reinterpret_cast<const short8*>(wp + (kk << 5));
  }

  const int arow = (g << 4) + lr16;
  const size_t aoff = ((size_t)arow << 10) + (ks << 7) + k8;

  const int b_l = tid >> 5;
  const int j = tid & 31;
  const int b_g = (g << 4) + b_l;
  const int hcol = hc0 + j;

  float cs = 0.f;

  auto xload = [&](int t) -> uint2 {
    return *reinterpret_cast<const uint2*>(
        xp + (((size_t)((t << 6) + b_g)) << 12) + (hcol << 2));
  };

  auto step = [&](int t, uint2 xv) {
    if (t > 0) {
      const unsigned short* ab = hbuf + ((size_t)(t & 1) << 16) + aoff;
      short8 av[4];
#pragma unroll
      for (int kk = 0; kk < 4; ++kk) {
        const unsigned short* p = ab + (kk << 5);
        asm volatile("global_load_dwordx4 %0, %1, off sc0 sc1"
                     : "=v"(av[kk]) : "v"(p) : "memory");
      }
      asm volatile("s_waitcnt vmcnt(0)" ::: "memory");
      __builtin_amdgcn_sched_barrier(0);
      f32x4 acc[8] = {{0.f,0.f,0.f,0.f},{0.f,0.f,0.f,0.f},{0.f,0.f,0.f,0.f},{0.f,0.f,0.f,0.f},
                      {0.f,0.f,0.f,0.f},{0.f,0.f,0.f,0.f},{0.f,0.f,0.f,0.f},{0.f,0.f,0.f,0.f}};
#pragma unroll
      for (int kk = 0; kk < 4; ++kk)
#pragma unroll
        for (int nn = 0; nn < 8; ++nn)
          acc[nn] = MFMA16(av[kk], bf[nn][kk], acc[nn]);
#pragma unroll
      for (int nn = 0; nn < 8; ++nn)
#pragma unroll
        for (int q = 0; q < 4; ++q) {
          int bq = ((l >> 4) << 2) + q;
          part[(((ks << 4) + bq) << 7) + (nn << 4) + lr16] = acc[nn][q];
        }
    }
    __syncthreads();

    float hv, cv;
    unsigned short h16;
    {
      float gi = bf2f((unsigned short)(xv.x)), gf = bf2f((unsigned short)(xv.x >> 16));
      float gg = bf2f((unsigned short)(xv.y)), go = bf2f((unsigned short)(xv.y >> 16));
      if (t > 0) {
        float si = 0.f, sf = 0.f, sg = 0.f, so = 0.f;
#pragma unroll
        for (int ksx = 0; ksx < 8; ++ksx) {
          const float* p = part + (((ksx << 4) + b_l) << 7) + j;
          si += p[0]; sf += p[32]; sg += p[64]; so += p[96];
        }
        gi += si; gf += sf; gg += sg; go += so;
      }
      float iv = 1.f / (1.f + __expf(-gi));
      float fv = 1.f / (1.f + __expf(-gf));
      float gv = tanhf(gg);
      float ov = 1.f / (1.f + __expf(-go));
      cs = fv * cs + iv * gv;
      hv = ov * tanhf(cs);
      cv = cs;
      h16 = f2bf(hv);
      AS(hbuf + ((size_t)((t + 1) & 1) << 16) + ((size_t)b_g << 10) + hcol, h16);
    }
    asm volatile("s_waitcnt vmcnt(0)" ::: "memory");
    __syncthreads();
    if (tid == 0) AS(&gflags[w], t + 1);

    AS(out_bf + ((((size_t)t << 6) + b_g) << 10) + hcol, h16);
    if (t == 511) {
      hn[((size_t)b_g << 10) + hcol] = hv;
      cn[((size_t)b_g << 10) + hcol] = cv;
    } else {
      const int base = ks << 2;
      for (;;) {
        int f = (l < 4) ? AL(&gflags[base + l]) : 0x7fffffff;
        if (__all(f > t)) break;
        __builtin_amdgcn_s_sleep(1);
      }
    }
  };

  uint2 zz = {0u, 0u};
  uint2 xA[4] = {zz, zz, zz, zz}, xB[4] = {zz, zz, zz, zz};
#pragma unroll
  for (int s = 0; s < 4; ++s) xA[s] = xload(s);
  for (int tc = 0; tc < 512; tc += 8) {
#pragma unroll
    for (int s = 0; s < 4; ++s) xB[s] = xload(tc + 4 + s);
#pragma unroll
    for (int s = 0; s < 4; ++s) step(tc + s, xA[s]);
    if (tc + 8 < 512) {
#pragma unroll
      for (int s = 0; s < 4; ++s) xA[s] = xload(tc + 8 + s);
    }
#pragma unroll
    for (int s = 0; s < 4; ++s) step(tc + 4 + s, xB[s]);
  }

  asm volatile("s_waitcnt vmcnt(0)" ::: "memory");
  __syncthreads();
  if (tid == 0) AS(&gflags[w], 1000);

  // ---- tail producer: partner rec1 WG's xp1 chunks 5..7 ----
  if (tid == 0) {
    for (;;) {
      bool ok = true;
      for (int i = 0; i < 32; ++i)
        if (AL(&gflags[i]) < 1000) { ok = false; break; }
      if (ok) break;
      __builtin_amdgcn_s_sleep(16);
    }
  }
  __syncthreads();
  for (int c = 5; c < 8; ++c) {
    const int need = (c - 1) << 6;
    if (tid == 0) {
      while (AL(pflag1) < need) __builtin_amdgcn_s_sleep(16);
    }
    __syncthreads();
    gemm_chunk(out_bf, Wih1, bias1,
               xpp_partner + ((size_t)(c & 1) << 17),
               gflags, gmin_lds,
               (char*)part, g, hc0, c, tid, l, ks, lr16, k8);
    if (tid == 0) AS(fx_self, c + 1);
  }
}

// ---------------- layer-1: chunks 0..4 self-gemm (mb-paced), 5..7 from partner ------
__device__ __forceinline__ void layer1_body(
    const unsigned short* __restrict__ out0,
    const unsigned short* __restrict__ Wih1,
    const float* __restrict__ bias1,
    const unsigned short* __restrict__ Whh1,
    unsigned short* __restrict__ xpp,      // private 2 x 131072 ushorts (ping-pong, sc1)
    unsigned short* __restrict__ hbuf,
    int* __restrict__ gflags0,
    int* __restrict__ gflags1,
    const int* __restrict__ fx_self,
    float* __restrict__ outf,
    float* __restrict__ hn, float* __restrict__ cn,
    float* part, int* gmin_lds, int u, int g) {
  const int tid = threadIdx.x;
  const int l = tid & 63, ks = tid >> 6;
  const int hc0 = u << 5;
  const int lr16 = l & 15, k8 = (l >> 4) << 3;

  short8 bf[8][4];
#pragma unroll
  for (int nn = 0; nn < 8; ++nn) {
    const int c_wg = (nn << 4) + lr16;
    const unsigned short* wp =
        Whh1 + ((size_t)(((c_wg >> 5) << 10) + hc0 + (c_wg & 31)) << 10) + (ks << 7) + k8;
#pragma unroll
    for (int kk = 0; kk < 4; ++kk)
      bf[nn][kk] = *reinterpret_cast<const short8*>(wp + (kk << 5));
  }

  const int arow = (g << 4) + lr16;
  const size_t aoff = ((size_t)arow << 10) + (ks << 7) + k8;
  const int b_l = tid >> 5, j = tid & 31;
  const int b_g = (g << 4) + b_l;
  const int hcol = hc0 + j;

  float cs = 0.f;

  for (int c = 0; c < 8; ++c) {
    if (c < 5) {
      gemm_chunk(out0, Wih1, bias1,
                 xpp + ((size_t)(c & 1) << 17),
                 gflags0, gmin_lds,
                 (char*)part, g, hc0, c, tid, l, ks, lr16, k8);
    } else {
      if (tid == 0) {
        while (AL(fx_self) < c + 1) __builtin_amdgcn_s_sleep(16);
      }
      __syncthreads();
    }

    const unsigned short* xb = xpp + ((size_t)(c & 1) << 17);
    for (int ti = 0; ti < 64; ++ti) {
      const int t = (c << 6) + ti;
      uint2 xv;
      {
        const unsigned short* p = xb + (((ti << 4) + b_l) << 7) + (j << 2);
        asm volatile("global_load_dwordx2 %0, %1, off sc0 sc1"
                     : "=v"(xv) : "v"(p) : "memory");
      }

      if (t > 0) {
        const unsigned short* ab = hbuf + ((size_t)(t & 1) << 16) + aoff;
        short8 av[4];
#pragma unroll
        for (int kk = 0; kk < 4; ++kk) {
          const unsigned short* p = ab + (kk << 5);
          asm volatile("global_load_dwordx4 %0, %1, off sc0 sc1"
                       : "=v"(av[kk]) : "v"(p) : "memory");
        }
        asm volatile("s_waitcnt vmcnt(0)" ::: "memory");
        __builtin_amdgcn_sched_barrier(0);
        f32x4 acc[8] = {{0.f,0.f,0.f,0.f},{0.f,0.f,0.f,0.f},{0.f,0.f,0.f,0.f},{0.f,0.f,0.f,0.f},
                        {0.f,0.f,0.f,0.f},{0.f,0.f,0.f,0.f},{0.f,0.f,0.f,0.f},{0.f,0.f,0.f,0.f}};
#pragma unroll
        for (int kk = 0; kk < 4; ++kk)
#pragma unroll
          for (int nn = 0; nn < 8; ++nn)
            acc[nn] = MFMA16(av[kk], bf[nn][kk], acc[nn]);
#pragma unroll
        for (int nn = 0; nn < 8; ++nn)
#pragma unroll
          for (int q = 0; q < 4; ++q) {
            int bq = ((l >> 4) << 2) + q;
            part[(((ks << 4) + bq) << 7) + (nn << 4) + lr16] = acc[nn][q];
          }
      } else {
        asm volatile("s_waitcnt vmcnt(0)" ::: "memory");  // xv ready (t==0 path)
      }
      __syncthreads();

      float hv, cv;
      unsigned short h16;
      {
        float gi = bf2f((unsigned short)(xv.x)), gf = bf2f((unsigned short)(xv.x >> 16));
        float gg = bf2f((unsigned short)(xv.y)), go = bf2f((unsigned short)(xv.y >> 16));
        if (t > 0) {
          float si = 0.f, sf = 0.f, sg = 0.f, so = 0.f;
#pragma unroll
          for (int ksx = 0; ksx < 8; ++ksx) {
            const float* p = part + (((ksx << 4) + b_l) << 7) + j;
            si += p[0]; sf += p[32]; sg += p[64]; so += p[96];
          }
          gi += si; gf += sf; gg += sg; go += so;
        }
        float iv = 1.f / (1.f + __expf(-gi));
        float fv = 1.f / (1.f + __expf(-gf));
        float gv = tanhf(gg);
        float ov = 1.f / (1.f + __expf(-go));
        cs = fv * cs + iv * gv;
        hv = ov * tanhf(cs);
        cv = cs;
        h16 = f2bf(hv);
        AS(hbuf + ((size_t)((t + 1) & 1) << 16) + ((size_t)b_g << 10) + hcol, h16);
      }
      asm volatile("s_waitcnt vmcnt(0)" ::: "memory");
      __syncthreads();
      if (tid == 0) AS(&gflags1[u], t + 1);

      outf[((((size_t)b_g << 9) + t) << 10) + hcol] = hv;
      if (t == 511) {
        hn[((size_t)b_g << 10) + hcol] = hv;
        cn[((size_t)b_g << 10) + hcol] = cv;
      } else {
        const int base = ks << 2;
        for (;;) {
          int f = (l < 4) ? AL(&gflags1[base + l]) : 0x7fffffff;
          if (__all(f > t)) break;
          __builtin_amdgcn_s_sleep(1);
        }
      }
    }
  }
}

// ---------------- fused: rec0+tail-producer (0..127) || rec1 (128..255) ------------
__global__ __launch_bounds__(512, 2) void k_fused(
    const unsigned short* __restrict__ xp0,
    const unsigned short* __restrict__ Whh0,
    unsigned short* __restrict__ hb0,
    int* __restrict__ flags0,
    unsigned short* __restrict__ out0,
    float* __restrict__ hn, float* __restrict__ cn,
    const unsigned short* __restrict__ Wih1,
    const float* __restrict__ bias1,
    const unsigned short* __restrict__ Whh1,
    unsigned short* __restrict__ xpp_all,
    unsigned short* __restrict__ hb1,
    int* __restrict__ flags1,
    int* __restrict__ fx,
    float* __restrict__ outf) {
  __shared__ float part[8 * 16 * 128];   // 64 KB
  __shared__ int gmin;                    // per-mb gate cache
  const int wg = blockIdx.x;
  if (wg < 128) {
    rec0_body(xp0, Whh0, hb0, flags0 + ((wg >> 5) << 8), out0, hn, cn,
              Wih1, bias1,
              xpp_all + ((size_t)wg << 18),
              &flags1[((wg >> 5) << 8) + (wg & 31)],
              &fx[wg],
              part, &gmin, wg & 31, wg >> 5);
  } else {
    const int w1 = wg - 128;
    layer1_body(out0, Wih1, bias1, Whh1,
                xpp_all + ((size_t)w1 << 18),
                hb1, flags0 + ((w1 >> 5) << 8), flags1 + ((w1 >> 5) << 8),
                &fx[w1],
                outf, hn + 65536, cn + 65536,
                part, &gmin, w1 & 31, w1 >> 5);
  }
}

// ---------------- launch ----------------
extern "C" void kernel_launch(void* const* d_in, const int* in_sizes, int n_in,
                              void* d_out, int out_size, void* d_ws, size_t ws_size,
                              hipStream_t stream) {
  (void)in_sizes; (void)n_in; (void)out_size; (void)ws_size;
  const float* x    = (const float*)d_in[0];
  const float* Wih0 = (const float*)d_in[1];
  const float* bih0 = (const float*)d_in[2];
  const float* Whh0 = (const float*)d_in[3];
  const float* bhh0 = (const float*)d_in[4];
  const float* Wih1 = (const float*)d_in[5];
  const float* bih1 = (const float*)d_in[6];
  const float* Whh1 = (const float*)d_in[7];
  const float* bhh1 = (const float*)d_in[8];
  float* dout = (float*)d_out;

  char* ws = (char*)d_ws;
  int*            flags0 = (int*)ws;                         // 4 KB
  int*            flags1 = (int*)(ws + 4096);                // 4 KB
  int*            fx     = (int*)(ws + 8192);                // 4 KB (128 used)
  unsigned short* hb0    = (unsigned short*)(ws + 12288);    // 256 KB
  unsigned short* hb1    = (unsigned short*)(ws + 274432);   // 256 KB
  float*          bias0  = (float*)(ws + 536576);            // 16 KB
  float*          bias1  = (float*)(ws + 552960);            // 16 KB
  unsigned short* wbf    = (unsigned short*)(ws + 569344);   // 32 MB: ih0,hh0,ih1,hh1
  unsigned short* xbf    = wbf + 16777216;                   // 64 MB (x bf16; reused as xpp)
  unsigned short* out0   = xbf + 33554432;                   // 64 MB
  unsigned short* xpb    = out0 + 33554432;                  // 256 MB (xp0)

  hipMemsetAsync(flags0, 0, 12288, stream);

  // merged prep: x cvt + 4 weight cvts + biases (one launch)
  k_prep<<<2048, 256, 0, stream>>>(x, Wih0, Whh0, Wih1, Whh1,
                                   bih0, bhh0, bih1, bhh1,
                                   xbf, wbf, bias0, bias1);

  float* hn = dout + 33554432;
  float* cn = dout + 33554432 + 131072;

  // layer 0 xp (serial; xbf becomes dead afterward and is reused as xpp)
  k_gemm<<<8192, 256, 0, stream>>>(xbf, wbf + 0, bias0, xpb, 0);

  // fused pipeline: rec0 (+ tail gemm producer) || rec1 (mb-paced gemm)
  k_fused<<<256, 512, 0, stream>>>(xpb, wbf + 4194304, hb0, flags0,
                                   out0, hn, cn,
                                   wbf + 8388608, bias1, wbf + 12582912,
                                   xbf, hb1, flags1, fx, dout);
}